// Round 3
// baseline (897.690 us; speedup 1.0000x reference)
//
#include <hip/hip_runtime.h>

typedef __attribute__((ext_vector_type(8))) short bf16x8;
typedef __attribute__((ext_vector_type(4))) float f32x4;
typedef unsigned short u16;
typedef unsigned int u32;

#define B_ 8
#define T_ 512
#define C_ 1024
#define I_ 4096
#define H_ 16
#define Dh_ 64
#define BT (B_*T_)
#define NH (B_*H_)

// ---------------- helpers ----------------
__device__ __forceinline__ float bf2f(u16 u) {
  return __uint_as_float(((u32)u) << 16);
}
__device__ __forceinline__ u16 f2bf(float f) {
  u32 u = __float_as_uint(f);
  u32 r = u + 0x7FFFu + ((u >> 16) & 1u);
  return (u16)(r >> 16);
}
__device__ __forceinline__ float wredMax(float v) {
#pragma unroll
  for (int o = 32; o; o >>= 1) v = fmaxf(v, __shfl_xor(v, o));
  return v;
}
__device__ __forceinline__ float wredSum(float v) {
#pragma unroll
  for (int o = 32; o; o >>= 1) v += __shfl_xor(v, o);
  return v;
}

// ---------------- small kernels ----------------
__global__ void k_init(u32* s) { if (threadIdx.x < 16) s[threadIdx.x] = 0u; }

__global__ __launch_bounds__(256) void k_absmax(const float* __restrict__ x, int n4, u32* __restrict__ amax) {
  int stride = gridDim.x * blockDim.x;
  float m = 0.f;
  for (int i = blockIdx.x * blockDim.x + threadIdx.x; i < n4; i += stride) {
    float4 v = ((const float4*)x)[i];
    m = fmaxf(m, fmaxf(fmaxf(fabsf(v.x), fabsf(v.y)), fmaxf(fabsf(v.z), fabsf(v.w))));
  }
  m = wredMax(m);
  if ((threadIdx.x & 63) == 0) atomicMax(amax, __float_as_uint(m));
}

__device__ __forceinline__ float fq1(float v, float s, float inv) {
  return fminf(fmaxf(rintf(v * inv), -127.f), 127.f) * s;
}

__global__ __launch_bounds__(256) void k_quant_f32(const float* __restrict__ x, u16* __restrict__ q, int n4,
                                                   const u32* __restrict__ amax) {
  float s = fmaxf(__uint_as_float(*amax) / 127.0f, 1e-8f);
  float inv = 1.0f / s;
  int stride = gridDim.x * blockDim.x;
  for (int i = blockIdx.x * blockDim.x + threadIdx.x; i < n4; i += stride) {
    float4 v = ((const float4*)x)[i];
    ushort4 o;
    o.x = f2bf(fq1(v.x, s, inv));
    o.y = f2bf(fq1(v.y, s, inv));
    o.z = f2bf(fq1(v.z, s, inv));
    o.w = f2bf(fq1(v.w, s, inv));
    ((ushort4*)q)[i] = o;
  }
}

__global__ __launch_bounds__(256) void k_quant_bf16(u16* __restrict__ x, int n8, const u32* __restrict__ amax) {
  float s = fmaxf(__uint_as_float(*amax) / 127.0f, 1e-8f);
  float inv = 1.0f / s;
  int stride = gridDim.x * blockDim.x;
  for (int i = blockIdx.x * blockDim.x + threadIdx.x; i < n8; i += stride) {
    uint4 d = ((uint4*)x)[i];
    u16* e = (u16*)&d;
#pragma unroll
    for (int j = 0; j < 8; j++) e[j] = f2bf(fq1(bf2f(e[j]), s, inv));
    ((uint4*)x)[i] = d;
  }
}

// LayerNorm row (C=1024) + global absmax of output
__global__ __launch_bounds__(256) void k_ln(const float* __restrict__ x, const float* __restrict__ g,
                                            const float* __restrict__ b, float* __restrict__ y,
                                            u32* __restrict__ amax) {
  int row = blockIdx.x;
  int t = threadIdx.x;
  float4 v = ((const float4*)(x + (long)row * C_))[t];
  float s1 = v.x + v.y + v.z + v.w;
  float s2 = v.x * v.x + v.y * v.y + v.z * v.z + v.w * v.w;
  s1 = wredSum(s1);
  s2 = wredSum(s2);
  __shared__ float red[8];
  int wid = t >> 6, lane = t & 63;
  if (lane == 0) { red[wid] = s1; red[4 + wid] = s2; }
  __syncthreads();
  s1 = red[0] + red[1] + red[2] + red[3];
  s2 = red[4] + red[5] + red[6] + red[7];
  float mean = s1 * (1.0f / C_);
  float var = s2 * (1.0f / C_) - mean * mean;
  float inv = rsqrtf(var + 1e-5f);
  float4 gv = ((const float4*)g)[t];
  float4 bv = ((const float4*)b)[t];
  float4 o;
  o.x = (v.x - mean) * inv * gv.x + bv.x;
  o.y = (v.y - mean) * inv * gv.y + bv.y;
  o.z = (v.z - mean) * inv * gv.z + bv.z;
  o.w = (v.w - mean) * inv * gv.w + bv.w;
  ((float4*)(y + (long)row * C_))[t] = o;
  float m = fmaxf(fmaxf(fabsf(o.x), fabsf(o.y)), fmaxf(fabsf(o.z), fabsf(o.w)));
  m = wredMax(m);
  if (lane == 0) atomicMax(amax, __float_as_uint(m));
}

// softmax over rows of 512, bf16 in-place; one wave per row
__global__ __launch_bounds__(256) void k_softmax(u16* __restrict__ S) {
  int r = blockIdx.x * 4 + (threadIdx.x >> 6);
  int lane = threadIdx.x & 63;
  u16* row = S + (long)r * T_ + lane * 8;
  uint4 d = *(const uint4*)row;
  u16* e = (u16*)&d;
  float v[8];
  float mx = -3.0e38f;
#pragma unroll
  for (int j = 0; j < 8; j++) { v[j] = bf2f(e[j]); mx = fmaxf(mx, v[j]); }
  mx = wredMax(mx);
  float sum = 0.f;
#pragma unroll
  for (int j = 0; j < 8; j++) { v[j] = expf(v[j] - mx); sum += v[j]; }
  sum = wredSum(sum);
  float inv = 1.0f / sum;
#pragma unroll
  for (int j = 0; j < 8; j++) e[j] = f2bf(v[j] * inv);
  *(uint4*)row = d;
}

// ---------------- unified MFMA GEMM ----------------
// C[M,N] = A[M,K] * B^T + epilogue.  B normally [N,K] row-major; EPI==5: B is [K,N].
// Batched via blockIdx.z: bb=z/bH, hh=z%bH; per-operand (b,h) strides.
// EPI: 0 = +bias -> bf16
//      1 = +bias +resid(f32) -> f32
//      2 = +bias, gelu, absmax -> bf16
//      3 = +bias +resid(f32) -> f32 (final output)
//      4 = *scale + mask-ext -> bf16 (scores)
//      5 = absmax -> bf16 (PV; B in [K,N])
template <int BN, int EPI>
__global__ __launch_bounds__(256) void k_gemm(
    const u16* __restrict__ A, int lda, long sAb, long sAh,
    const u16* __restrict__ Bm, int ldb, long sBb, long sBh,
    const float* __restrict__ bias,
    void* __restrict__ Cp, int ldc, long sCb, long sCh,
    int M, int N, int K, int bH,
    const float* __restrict__ resid,
    u32* __restrict__ amax,
    const float* __restrict__ mask, float scale) {
  constexpr int BM = 128, BK = 32;
  constexpr int MF = 4;
  constexpr int NF = (BN / 2) / 16;
  __shared__ u16 As[BM][BK];
  __shared__ u16 Bs[BN][BK];
  const int tid = threadIdx.x;
  const int wid = tid >> 6, lane = tid & 63;
  const int wr = wid >> 1, wc = wid & 1;
  const int bz = blockIdx.z;
  const int bb = bz / bH, hh = bz % bH;
  const u16* Ab = A + bb * sAb + hh * sAh + (long)blockIdx.y * BM * lda;
  const u16* Bb;
  if (EPI == 5)
    Bb = Bm + bb * sBb + hh * sBh + blockIdx.x * BN;  // [K,N]: column offset
  else
    Bb = Bm + bb * sBb + hh * sBh + (long)blockIdx.x * BN * ldb;

  f32x4 acc[MF][NF];
#pragma unroll
  for (int m = 0; m < MF; m++)
#pragma unroll
    for (int n = 0; n < NF; n++) acc[m][n] = (f32x4){0.f, 0.f, 0.f, 0.f};

  const int lr = lane & 15;
  const int lk = (lane >> 4) * 8;

  for (int k0 = 0; k0 < K; k0 += BK) {
    __syncthreads();
    // stage A: BM*BK elems, 8 per chunk
    {
      int c = tid;
#pragma unroll
      for (int it = 0; it < (BM * BK / 8) / 256; ++it, c += 256) {
        int row = c >> 2, col8 = (c & 3) * 8;
        *(uint4*)&As[row][col8] = *(const uint4*)(Ab + (long)row * lda + k0 + col8);
      }
    }
    if (EPI == 5) {
      // Bs[n][kk] = Bb[(k0+kk)*ldb + n]; BN==64 here
      int kk = tid >> 3;
      int n0 = (tid & 7) * 8;
      uint4 t4 = *(const uint4*)(Bb + (long)(k0 + kk) * ldb + n0);
      u16* tv = (u16*)&t4;
#pragma unroll
      for (int j = 0; j < 8; j++) Bs[n0 + j][kk] = tv[j];
    } else {
      int c = tid;
#pragma unroll
      for (int it = 0; it < (BN * BK / 8) / 256; ++it, c += 256) {
        int row = c >> 2, col8 = (c & 3) * 8;
        *(uint4*)&Bs[row][col8] = *(const uint4*)(Bb + (long)row * ldb + k0 + col8);
      }
    }
    __syncthreads();

    bf16x8 af[MF], bfr[NF];
#pragma unroll
    for (int m = 0; m < MF; m++) af[m] = *(const bf16x8*)&As[wr * 64 + m * 16 + lr][lk];
#pragma unroll
    for (int n = 0; n < NF; n++) bfr[n] = *(const bf16x8*)&Bs[wc * (BN / 2) + n * 16 + lr][lk];
#pragma unroll
    for (int m = 0; m < MF; m++)
#pragma unroll
      for (int n = 0; n < NF; n++)
        acc[m][n] = __builtin_amdgcn_mfma_f32_16x16x32_bf16(af[m], bfr[n], acc[m][n], 0, 0, 0);
  }

  const int rowBase = blockIdx.y * BM + wr * 64;
  const int colBase = blockIdx.x * BN + wc * (BN / 2);
  const long cb = bb * sCb + hh * sCh;
  float lmax = 0.f;
#pragma unroll
  for (int m = 0; m < MF; m++) {
    int row0 = rowBase + m * 16 + (lane >> 4) * 4;
#pragma unroll
    for (int n = 0; n < NF; n++) {
      int col = colBase + n * 16 + lr;
      float bs = 0.f, ext = 0.f;
      if (EPI == 0 || EPI == 1 || EPI == 2 || EPI == 3) bs = bias[col];
      if (EPI == 4) ext = (1.0f - mask[bb * T_ + col]) * -10000.0f;
#pragma unroll
      for (int j = 0; j < 4; j++) {
        int row = row0 + j;
        long idx = cb + (long)row * ldc + col;
        float v = acc[m][n][j];
        if (EPI == 0) {
          ((u16*)Cp)[idx] = f2bf(v + bs);
        } else if (EPI == 1) {
          ((float*)Cp)[idx] = v + bs + resid[idx];
        } else if (EPI == 2) {
          v += bs;
          v = 0.5f * v * (1.0f + erff(v * 0.70710678118f));
          lmax = fmaxf(lmax, fabsf(v));
          ((u16*)Cp)[idx] = f2bf(v);
        } else if (EPI == 3) {
          ((float*)Cp)[idx] = v + bs + resid[idx];
        } else if (EPI == 4) {
          ((u16*)Cp)[idx] = f2bf(v * scale + ext);
        } else {
          lmax = fmaxf(lmax, fabsf(v));
          ((u16*)Cp)[idx] = f2bf(v);
        }
      }
    }
  }
  if (EPI == 2 || EPI == 5) {
    lmax = wredMax(lmax);
    if (lane == 0) atomicMax(amax, __float_as_uint(lmax));
  }
}

// ---------------- host ----------------
extern "C" void kernel_launch(void* const* d_in, const int* in_sizes, int n_in,
                              void* d_out, int out_size, void* d_ws, size_t ws_size,
                              hipStream_t stream) {
  const float* hidden = (const float*)d_in[0];
  const float* mask = (const float*)d_in[1];
  const float* ln1g = (const float*)d_in[2];
  const float* ln1b = (const float*)d_in[3];
  const float* ln2g = (const float*)d_in[4];
  const float* ln2b = (const float*)d_in[5];
  const float* w_qkv = (const float*)d_in[6];
  const float* b_qkv = (const float*)d_in[7];
  const float* w_out = (const float*)d_in[8];
  const float* b_out = (const float*)d_in[9];
  const float* w1 = (const float*)d_in[10];
  const float* b1 = (const float*)d_in[11];
  const float* w2 = (const float*)d_in[12];
  const float* b2 = (const float*)d_in[13];

  char* ws = (char*)d_ws;
  u32* sc = (u32*)ws;  // [0]wqkv [1]wout [2]w1 [3]w2 [4]x1 [5]O [6]x2 [7]y1
  u16* wq_qkv = (u16*)(ws + 256);
  u16* wq_out = (u16*)(ws + 6291712);
  u16* wq_w1 = (u16*)(ws + 8388864);
  u16* wq_w2 = (u16*)(ws + 16777472);
  float* x1 = (float*)(ws + 25166080);   // also x2
  u16* xq = (u16*)(ws + 41943296);       // also x2q
  u16* qkv = (u16*)(ws + 50331904);
  u16* S = (u16*)(ws + 75497728);        // scores/P; later y1 (raw+quant)
  u16* O = (u16*)(ws + 142606592);
  float* hbuf = (float*)(ws + 150995200);
  // total ws use: 167,772,416 bytes

  k_init<<<1, 64, 0, stream>>>(sc);

  // weight fake-quant
  k_absmax<<<512, 256, 0, stream>>>(w_qkv, 3 * C_ * C_ / 4, sc + 0);
  k_absmax<<<512, 256, 0, stream>>>(w_out, C_ * C_ / 4, sc + 1);
  k_absmax<<<512, 256, 0, stream>>>(w1, I_ * C_ / 4, sc + 2);
  k_absmax<<<512, 256, 0, stream>>>(w2, C_ * I_ / 4, sc + 3);
  k_quant_f32<<<512, 256, 0, stream>>>(w_qkv, wq_qkv, 3 * C_ * C_ / 4, sc + 0);
  k_quant_f32<<<512, 256, 0, stream>>>(w_out, wq_out, C_ * C_ / 4, sc + 1);
  k_quant_f32<<<512, 256, 0, stream>>>(w1, wq_w1, I_ * C_ / 4, sc + 2);
  k_quant_f32<<<512, 256, 0, stream>>>(w2, wq_w2, C_ * I_ / 4, sc + 3);

  // LN1 + fq(x)
  k_ln<<<BT, 256, 0, stream>>>(hidden, ln1g, ln1b, x1, sc + 4);
  k_quant_f32<<<512, 256, 0, stream>>>(x1, xq, BT * C_ / 4, sc + 4);

  // qkv = xq @ wq_qkv^T + b  -> bf16 [4096,3072]
  k_gemm<128, 0><<<dim3(24, 32, 1), 256, 0, stream>>>(
      xq, C_, 0, 0, wq_qkv, C_, 0, 0, b_qkv, qkv, 3 * C_, 0, 0,
      BT, 3 * C_, C_, 1, nullptr, nullptr, nullptr, 0.f);

  // scores = Q K^T * scale + ext -> bf16 [128][512][512]
  k_gemm<128, 4><<<dim3(4, 4, NH), 256, 0, stream>>>(
      qkv, 3 * C_, (long)T_ * 3 * C_, Dh_,
      qkv + C_, 3 * C_, (long)T_ * 3 * C_, Dh_,
      nullptr,
      S, T_, (long)H_ * T_ * T_, (long)T_ * T_,
      T_, T_, Dh_, H_, nullptr, nullptr, mask, 0.125f);

  k_softmax<<<NH * T_ / 4, 256, 0, stream>>>(S);

  // O = P @ V  (B in [K,N])  -> bf16 [4096,1024] in (b,t,h*64+d) layout, + absmax
  k_gemm<64, 5><<<dim3(1, 4, NH), 256, 0, stream>>>(
      S, T_, (long)H_ * T_ * T_, (long)T_ * T_,
      qkv + 2 * C_, 3 * C_, (long)T_ * 3 * C_, Dh_,
      nullptr,
      O, C_, (long)T_ * C_, (long)Dh_,
      T_, Dh_, T_, H_, nullptr, sc + 5, nullptr, 0.f);

  k_quant_bf16<<<512, 256, 0, stream>>>(O, BT * C_ / 8, sc + 5);

  // h = hidden + Oq @ wq_out^T + b  -> f32
  k_gemm<128, 1><<<dim3(8, 32, 1), 256, 0, stream>>>(
      O, C_, 0, 0, wq_out, C_, 0, 0, b_out, hbuf, C_, 0, 0,
      BT, C_, C_, 1, hidden, nullptr, nullptr, 0.f);

  // LN2 + fq
  k_ln<<<BT, 256, 0, stream>>>(hbuf, ln2g, ln2b, x1, sc + 6);
  k_quant_f32<<<512, 256, 0, stream>>>(x1, xq, BT * C_ / 4, sc + 6);

  // y1 = gelu(xq @ wq_w1^T + b1) -> bf16 [4096,4096], + absmax
  k_gemm<128, 2><<<dim3(32, 32, 1), 256, 0, stream>>>(
      xq, C_, 0, 0, wq_w1, C_, 0, 0, b1, S, I_, 0, 0,
      BT, I_, C_, 1, nullptr, sc + 7, nullptr, 0.f);

  k_quant_bf16<<<512, 256, 0, stream>>>(S, BT * I_ / 8, sc + 7);

  // out = h + y1q @ wq_w2^T + b2 -> f32 d_out
  k_gemm<128, 3><<<dim3(8, 32, 1), 256, 0, stream>>>(
      S, I_, 0, 0, wq_w2, I_, 0, 0, b2, d_out, C_, 0, 0,
      BT, C_, I_, 1, hbuf, nullptr, nullptr, 0.f);
}

// Round 4
// 456.434 us; speedup vs baseline: 1.9667x; 1.9667x over previous
//
#include <hip/hip_runtime.h>

typedef __attribute__((ext_vector_type(8))) short bf16x8;
typedef __attribute__((ext_vector_type(4))) float f32x4;
typedef unsigned short u16;
typedef unsigned int u32;

#define B_ 8
#define T_ 512
#define C_ 1024
#define I_ 4096
#define H_ 16
#define Dh_ 64
#define BT (B_*T_)
#define NH (B_*H_)

// ---------------- helpers ----------------
__device__ __forceinline__ float bf2f(u16 u) {
  return __uint_as_float(((u32)u) << 16);
}
__device__ __forceinline__ u16 f2bf(float f) {
  u32 u = __float_as_uint(f);
  u32 r = u + 0x7FFFu + ((u >> 16) & 1u);
  return (u16)(r >> 16);
}
__device__ __forceinline__ float wredMax(float v) {
#pragma unroll
  for (int o = 32; o; o >>= 1) v = fmaxf(v, __shfl_xor(v, o));
  return v;
}
__device__ __forceinline__ float wredSum(float v) {
#pragma unroll
  for (int o = 32; o; o >>= 1) v += __shfl_xor(v, o);
  return v;
}
// Conditional atomic: only RMW if our value beats the currently visible max.
// Stale reads are always <= true max (monotone), so skipping is safe.
__device__ __forceinline__ void condAtomicMax(u32* amax, float bm) {
  u32 b = __float_as_uint(bm);  // bm >= 0 so uint compare == float compare
  if (b > *(volatile u32*)amax) atomicMax(amax, b);
}

// ---------------- small kernels ----------------
__global__ void k_init(u32* s) { if (threadIdx.x < 16) s[threadIdx.x] = 0u; }

__global__ __launch_bounds__(256) void k_absmax(const float* __restrict__ x, int n4, u32* __restrict__ amax) {
  int stride = gridDim.x * blockDim.x;
  float m = 0.f;
  for (int i = blockIdx.x * blockDim.x + threadIdx.x; i < n4; i += stride) {
    float4 v = ((const float4*)x)[i];
    m = fmaxf(m, fmaxf(fmaxf(fabsf(v.x), fabsf(v.y)), fmaxf(fabsf(v.z), fabsf(v.w))));
  }
  m = wredMax(m);
  __shared__ float red[4];
  int tid = threadIdx.x;
  if ((tid & 63) == 0) red[tid >> 6] = m;
  __syncthreads();
  if (tid == 0) {
    float bm = fmaxf(fmaxf(red[0], red[1]), fmaxf(red[2], red[3]));
    condAtomicMax(amax, bm);
  }
}

__device__ __forceinline__ float fq1(float v, float s, float inv) {
  return fminf(fmaxf(rintf(v * inv), -127.f), 127.f) * s;
}

__global__ __launch_bounds__(256) void k_quant_f32(const float* __restrict__ x, u16* __restrict__ q, int n4,
                                                   const u32* __restrict__ amax) {
  float s = fmaxf(__uint_as_float(*amax) / 127.0f, 1e-8f);
  float inv = 1.0f / s;
  int stride = gridDim.x * blockDim.x;
  for (int i = blockIdx.x * blockDim.x + threadIdx.x; i < n4; i += stride) {
    float4 v = ((const float4*)x)[i];
    ushort4 o;
    o.x = f2bf(fq1(v.x, s, inv));
    o.y = f2bf(fq1(v.y, s, inv));
    o.z = f2bf(fq1(v.z, s, inv));
    o.w = f2bf(fq1(v.w, s, inv));
    ((ushort4*)q)[i] = o;
  }
}

__global__ __launch_bounds__(256) void k_quant_bf16(u16* __restrict__ x, int n8, const u32* __restrict__ amax) {
  float s = fmaxf(__uint_as_float(*amax) / 127.0f, 1e-8f);
  float inv = 1.0f / s;
  int stride = gridDim.x * blockDim.x;
  for (int i = blockIdx.x * blockDim.x + threadIdx.x; i < n8; i += stride) {
    uint4 d = ((uint4*)x)[i];
    u16* e = (u16*)&d;
#pragma unroll
    for (int j = 0; j < 8; j++) e[j] = f2bf(fq1(bf2f(e[j]), s, inv));
    ((uint4*)x)[i] = d;
  }
}

// LayerNorm row (C=1024) + global absmax of output (block-reduced, low-contention)
__global__ __launch_bounds__(256) void k_ln(const float* __restrict__ x, const float* __restrict__ g,
                                            const float* __restrict__ b, float* __restrict__ y,
                                            u32* __restrict__ amax) {
  int row = blockIdx.x;
  int t = threadIdx.x;
  float4 v = ((const float4*)(x + (long)row * C_))[t];
  float s1 = v.x + v.y + v.z + v.w;
  float s2 = v.x * v.x + v.y * v.y + v.z * v.z + v.w * v.w;
  s1 = wredSum(s1);
  s2 = wredSum(s2);
  __shared__ float red[8];
  int wid = t >> 6, lane = t & 63;
  if (lane == 0) { red[wid] = s1; red[4 + wid] = s2; }
  __syncthreads();
  s1 = red[0] + red[1] + red[2] + red[3];
  s2 = red[4] + red[5] + red[6] + red[7];
  float mean = s1 * (1.0f / C_);
  float var = s2 * (1.0f / C_) - mean * mean;
  float inv = rsqrtf(var + 1e-5f);
  float4 gv = ((const float4*)g)[t];
  float4 bv = ((const float4*)b)[t];
  float4 o;
  o.x = (v.x - mean) * inv * gv.x + bv.x;
  o.y = (v.y - mean) * inv * gv.y + bv.y;
  o.z = (v.z - mean) * inv * gv.z + bv.z;
  o.w = (v.w - mean) * inv * gv.w + bv.w;
  ((float4*)(y + (long)row * C_))[t] = o;
  float m = fmaxf(fmaxf(fabsf(o.x), fabsf(o.y)), fmaxf(fabsf(o.z), fabsf(o.w)));
  m = wredMax(m);
  __syncthreads();  // all threads done reading red[] for the sums
  if (lane == 0) red[wid] = m;
  __syncthreads();
  if (t == 0) {
    float bm = fmaxf(fmaxf(red[0], red[1]), fmaxf(red[2], red[3]));
    condAtomicMax(amax, bm);
  }
}

// softmax over rows of 512, bf16 in-place; one wave per row
__global__ __launch_bounds__(256) void k_softmax(u16* __restrict__ S) {
  int r = blockIdx.x * 4 + (threadIdx.x >> 6);
  int lane = threadIdx.x & 63;
  u16* row = S + (long)r * T_ + lane * 8;
  uint4 d = *(const uint4*)row;
  u16* e = (u16*)&d;
  float v[8];
  float mx = -3.0e38f;
#pragma unroll
  for (int j = 0; j < 8; j++) { v[j] = bf2f(e[j]); mx = fmaxf(mx, v[j]); }
  mx = wredMax(mx);
  float sum = 0.f;
#pragma unroll
  for (int j = 0; j < 8; j++) { v[j] = expf(v[j] - mx); sum += v[j]; }
  sum = wredSum(sum);
  float inv = 1.0f / sum;
#pragma unroll
  for (int j = 0; j < 8; j++) e[j] = f2bf(v[j] * inv);
  *(uint4*)row = d;
}

// ---------------- unified MFMA GEMM ----------------
// C[M,N] = A[M,K] * B^T + epilogue.  B normally [N,K] row-major; EPI==5: B is [K,N].
// Batched via blockIdx.z: bb=z/bH, hh=z%bH; per-operand (b,h) strides.
// EPI: 0 = +bias -> bf16
//      1 = +bias +resid(f32) -> f32
//      2 = +bias, gelu, absmax -> bf16
//      3 = +bias +resid(f32) -> f32 (final output)
//      4 = *scale + mask-ext -> bf16 (scores)
//      5 = absmax -> bf16 (PV; B in [K,N])
template <int BN, int EPI>
__global__ __launch_bounds__(256) void k_gemm(
    const u16* __restrict__ A, int lda, long sAb, long sAh,
    const u16* __restrict__ Bm, int ldb, long sBb, long sBh,
    const float* __restrict__ bias,
    void* __restrict__ Cp, int ldc, long sCb, long sCh,
    int M, int N, int K, int bH,
    const float* __restrict__ resid,
    u32* __restrict__ amax,
    const float* __restrict__ mask, float scale) {
  constexpr int BM = 128, BK = 32;
  constexpr int MF = 4;
  constexpr int NF = (BN / 2) / 16;
  __shared__ u16 As[BM][BK];
  __shared__ u16 Bs[BN][BK];
  const int tid = threadIdx.x;
  const int wid = tid >> 6, lane = tid & 63;
  const int wr = wid >> 1, wc = wid & 1;
  const int bz = blockIdx.z;
  const int bb = bz / bH, hh = bz % bH;
  const u16* Ab = A + bb * sAb + hh * sAh + (long)blockIdx.y * BM * lda;
  const u16* Bb;
  if (EPI == 5)
    Bb = Bm + bb * sBb + hh * sBh + blockIdx.x * BN;  // [K,N]: column offset
  else
    Bb = Bm + bb * sBb + hh * sBh + (long)blockIdx.x * BN * ldb;

  f32x4 acc[MF][NF];
#pragma unroll
  for (int m = 0; m < MF; m++)
#pragma unroll
    for (int n = 0; n < NF; n++) acc[m][n] = (f32x4){0.f, 0.f, 0.f, 0.f};

  const int lr = lane & 15;
  const int lk = (lane >> 4) * 8;

  for (int k0 = 0; k0 < K; k0 += BK) {
    __syncthreads();
    // stage A: BM*BK elems, 8 per chunk
    {
      int c = tid;
#pragma unroll
      for (int it = 0; it < (BM * BK / 8) / 256; ++it, c += 256) {
        int row = c >> 2, col8 = (c & 3) * 8;
        *(uint4*)&As[row][col8] = *(const uint4*)(Ab + (long)row * lda + k0 + col8);
      }
    }
    if (EPI == 5) {
      // Bs[n][kk] = Bb[(k0+kk)*ldb + n]; BN==64 here
      int kk = tid >> 3;
      int n0 = (tid & 7) * 8;
      uint4 t4 = *(const uint4*)(Bb + (long)(k0 + kk) * ldb + n0);
      u16* tv = (u16*)&t4;
#pragma unroll
      for (int j = 0; j < 8; j++) Bs[n0 + j][kk] = tv[j];
    } else {
      int c = tid;
#pragma unroll
      for (int it = 0; it < (BN * BK / 8) / 256; ++it, c += 256) {
        int row = c >> 2, col8 = (c & 3) * 8;
        *(uint4*)&Bs[row][col8] = *(const uint4*)(Bb + (long)row * ldb + k0 + col8);
      }
    }
    __syncthreads();

    bf16x8 af[MF], bfr[NF];
#pragma unroll
    for (int m = 0; m < MF; m++) af[m] = *(const bf16x8*)&As[wr * 64 + m * 16 + lr][lk];
#pragma unroll
    for (int n = 0; n < NF; n++) bfr[n] = *(const bf16x8*)&Bs[wc * (BN / 2) + n * 16 + lr][lk];
#pragma unroll
    for (int m = 0; m < MF; m++)
#pragma unroll
      for (int n = 0; n < NF; n++)
        acc[m][n] = __builtin_amdgcn_mfma_f32_16x16x32_bf16(af[m], bfr[n], acc[m][n], 0, 0, 0);
  }

  const int rowBase = blockIdx.y * BM + wr * 64;
  const int colBase = blockIdx.x * BN + wc * (BN / 2);
  const long cb = bb * sCb + hh * sCh;
  float lmax = 0.f;
#pragma unroll
  for (int m = 0; m < MF; m++) {
    int row0 = rowBase + m * 16 + (lane >> 4) * 4;
#pragma unroll
    for (int n = 0; n < NF; n++) {
      int col = colBase + n * 16 + lr;
      float bs = 0.f, ext = 0.f;
      if (EPI == 0 || EPI == 1 || EPI == 2 || EPI == 3) bs = bias[col];
      if (EPI == 4) ext = (1.0f - mask[bb * T_ + col]) * -10000.0f;
#pragma unroll
      for (int j = 0; j < 4; j++) {
        int row = row0 + j;
        long idx = cb + (long)row * ldc + col;
        float v = acc[m][n][j];
        if (EPI == 0) {
          ((u16*)Cp)[idx] = f2bf(v + bs);
        } else if (EPI == 1) {
          ((float*)Cp)[idx] = v + bs + resid[idx];
        } else if (EPI == 2) {
          v += bs;
          v = 0.5f * v * (1.0f + erff(v * 0.70710678118f));
          lmax = fmaxf(lmax, fabsf(v));
          ((u16*)Cp)[idx] = f2bf(v);
        } else if (EPI == 3) {
          ((float*)Cp)[idx] = v + bs + resid[idx];
        } else if (EPI == 4) {
          ((u16*)Cp)[idx] = f2bf(v * scale + ext);
        } else {
          lmax = fmaxf(lmax, fabsf(v));
          ((u16*)Cp)[idx] = f2bf(v);
        }
      }
    }
  }
  if (EPI == 2 || EPI == 5) {
    __shared__ float redm[4];
    float wm = wredMax(lmax);
    if (lane == 0) redm[wid] = wm;
    __syncthreads();
    if (tid == 0) {
      float bm = fmaxf(fmaxf(redm[0], redm[1]), fmaxf(redm[2], redm[3]));
      condAtomicMax(amax, bm);
    }
  }
}

// ---------------- host ----------------
extern "C" void kernel_launch(void* const* d_in, const int* in_sizes, int n_in,
                              void* d_out, int out_size, void* d_ws, size_t ws_size,
                              hipStream_t stream) {
  const float* hidden = (const float*)d_in[0];
  const float* mask = (const float*)d_in[1];
  const float* ln1g = (const float*)d_in[2];
  const float* ln1b = (const float*)d_in[3];
  const float* ln2g = (const float*)d_in[4];
  const float* ln2b = (const float*)d_in[5];
  const float* w_qkv = (const float*)d_in[6];
  const float* b_qkv = (const float*)d_in[7];
  const float* w_out = (const float*)d_in[8];
  const float* b_out = (const float*)d_in[9];
  const float* w1 = (const float*)d_in[10];
  const float* b1 = (const float*)d_in[11];
  const float* w2 = (const float*)d_in[12];
  const float* b2 = (const float*)d_in[13];

  char* ws = (char*)d_ws;
  u32* sc = (u32*)ws;  // [0]wqkv [1]wout [2]w1 [3]w2 [4]x1 [5]O [6]x2 [7]y1
  u16* wq_qkv = (u16*)(ws + 256);
  u16* wq_out = (u16*)(ws + 6291712);
  u16* wq_w1 = (u16*)(ws + 8388864);
  u16* wq_w2 = (u16*)(ws + 16777472);
  float* x1 = (float*)(ws + 25166080);   // also x2
  u16* xq = (u16*)(ws + 41943296);       // also x2q
  u16* qkv = (u16*)(ws + 50331904);
  u16* S = (u16*)(ws + 75497728);        // scores/P; later y1 (raw+quant)
  u16* O = (u16*)(ws + 142606592);
  float* hbuf = (float*)(ws + 150995200);
  // total ws use: 167,772,416 bytes

  k_init<<<1, 64, 0, stream>>>(sc);

  // weight fake-quant
  k_absmax<<<512, 256, 0, stream>>>(w_qkv, 3 * C_ * C_ / 4, sc + 0);
  k_absmax<<<512, 256, 0, stream>>>(w_out, C_ * C_ / 4, sc + 1);
  k_absmax<<<512, 256, 0, stream>>>(w1, I_ * C_ / 4, sc + 2);
  k_absmax<<<512, 256, 0, stream>>>(w2, C_ * I_ / 4, sc + 3);
  k_quant_f32<<<512, 256, 0, stream>>>(w_qkv, wq_qkv, 3 * C_ * C_ / 4, sc + 0);
  k_quant_f32<<<512, 256, 0, stream>>>(w_out, wq_out, C_ * C_ / 4, sc + 1);
  k_quant_f32<<<512, 256, 0, stream>>>(w1, wq_w1, I_ * C_ / 4, sc + 2);
  k_quant_f32<<<512, 256, 0, stream>>>(w2, wq_w2, C_ * I_ / 4, sc + 3);

  // LN1 + fq(x)
  k_ln<<<BT, 256, 0, stream>>>(hidden, ln1g, ln1b, x1, sc + 4);
  k_quant_f32<<<512, 256, 0, stream>>>(x1, xq, BT * C_ / 4, sc + 4);

  // qkv = xq @ wq_qkv^T + b  -> bf16 [4096,3072]
  k_gemm<128, 0><<<dim3(24, 32, 1), 256, 0, stream>>>(
      xq, C_, 0, 0, wq_qkv, C_, 0, 0, b_qkv, qkv, 3 * C_, 0, 0,
      BT, 3 * C_, C_, 1, nullptr, nullptr, nullptr, 0.f);

  // scores = Q K^T * scale + ext -> bf16 [128][512][512]
  k_gemm<128, 4><<<dim3(4, 4, NH), 256, 0, stream>>>(
      qkv, 3 * C_, (long)T_ * 3 * C_, Dh_,
      qkv + C_, 3 * C_, (long)T_ * 3 * C_, Dh_,
      nullptr,
      S, T_, (long)H_ * T_ * T_, (long)T_ * T_,
      T_, T_, Dh_, H_, nullptr, nullptr, mask, 0.125f);

  k_softmax<<<NH * T_ / 4, 256, 0, stream>>>(S);

  // O = P @ V  (B in [K,N])  -> bf16 [4096,1024] in (b,t,h*64+d) layout, + absmax
  k_gemm<64, 5><<<dim3(1, 4, NH), 256, 0, stream>>>(
      S, T_, (long)H_ * T_ * T_, (long)T_ * T_,
      qkv + 2 * C_, 3 * C_, (long)T_ * 3 * C_, Dh_,
      nullptr,
      O, C_, (long)T_ * C_, (long)Dh_,
      T_, Dh_, T_, H_, nullptr, sc + 5, nullptr, 0.f);

  k_quant_bf16<<<512, 256, 0, stream>>>(O, BT * C_ / 8, sc + 5);

  // h = hidden + Oq @ wq_out^T + b  -> f32
  k_gemm<128, 1><<<dim3(8, 32, 1), 256, 0, stream>>>(
      O, C_, 0, 0, wq_out, C_, 0, 0, b_out, hbuf, C_, 0, 0,
      BT, C_, C_, 1, hidden, nullptr, nullptr, 0.f);

  // LN2 + fq
  k_ln<<<BT, 256, 0, stream>>>(hbuf, ln2g, ln2b, x1, sc + 6);
  k_quant_f32<<<512, 256, 0, stream>>>(x1, xq, BT * C_ / 4, sc + 6);

  // y1 = gelu(xq @ wq_w1^T + b1) -> bf16 [4096,4096], + absmax
  k_gemm<128, 2><<<dim3(32, 32, 1), 256, 0, stream>>>(
      xq, C_, 0, 0, wq_w1, C_, 0, 0, b1, S, I_, 0, 0,
      BT, I_, C_, 1, nullptr, sc + 7, nullptr, 0.f);

  k_quant_bf16<<<512, 256, 0, stream>>>(S, BT * I_ / 8, sc + 7);

  // out = h + y1q @ wq_w2^T + b2 -> f32 d_out
  k_gemm<128, 3><<<dim3(8, 32, 1), 256, 0, stream>>>(
      S, I_, 0, 0, wq_w2, I_, 0, 0, b2, d_out, C_, 0, 0,
      BT, C_, I_, 1, hbuf, nullptr, nullptr, 0.f);
}

// Round 6
// 432.123 us; speedup vs baseline: 2.0774x; 1.0563x over previous
//
#include <hip/hip_runtime.h>

typedef __attribute__((ext_vector_type(8))) short bf16x8;
typedef __attribute__((ext_vector_type(4))) float f32x4;
typedef unsigned short u16;
typedef unsigned int u32;

#define B_ 8
#define T_ 512
#define C_ 1024
#define I_ 4096
#define H_ 16
#define Dh_ 64
#define BT (B_*T_)
#define NH (B_*H_)

// ---------------- helpers ----------------
__device__ __forceinline__ float bf2f(u16 u) {
  return __uint_as_float(((u32)u) << 16);
}
__device__ __forceinline__ u16 f2bf(float f) {
  u32 u = __float_as_uint(f);
  u32 r = u + 0x7FFFu + ((u >> 16) & 1u);
  return (u16)(r >> 16);
}
__device__ __forceinline__ float wredMax(float v) {
#pragma unroll
  for (int o = 32; o; o >>= 1) v = fmaxf(v, __shfl_xor(v, o));
  return v;
}
__device__ __forceinline__ float wredSum(float v) {
#pragma unroll
  for (int o = 32; o; o >>= 1) v += __shfl_xor(v, o);
  return v;
}
// Conditional atomic: only RMW if our value beats the currently visible max.
// Stale reads are always <= true max (monotone), so skipping is safe.
__device__ __forceinline__ void condAtomicMax(u32* amax, float bm) {
  u32 b = __float_as_uint(bm);  // bm >= 0 so uint compare == float compare
  if (b > *(volatile u32*)amax) atomicMax(amax, b);
}
// global -> LDS direct copy, 16B per lane; lds dest is wave-uniform base,
// lane l lands at base + l*16 bytes.
__device__ __forceinline__ void gload16(const void* g, void* l) {
  __builtin_amdgcn_global_load_lds((const __attribute__((address_space(1))) void*)g,
                                   (__attribute__((address_space(3))) void*)l, 16, 0, 0);
}

// ---------------- small kernels ----------------
__global__ void k_init(u32* s) { if (threadIdx.x < 16) s[threadIdx.x] = 0u; }

__global__ __launch_bounds__(256) void k_absmax(const float* __restrict__ x, int n4, u32* __restrict__ amax) {
  int stride = gridDim.x * blockDim.x;
  float m = 0.f;
  for (int i = blockIdx.x * blockDim.x + threadIdx.x; i < n4; i += stride) {
    float4 v = ((const float4*)x)[i];
    m = fmaxf(m, fmaxf(fmaxf(fabsf(v.x), fabsf(v.y)), fmaxf(fabsf(v.z), fabsf(v.w))));
  }
  m = wredMax(m);
  __shared__ float red[4];
  int tid = threadIdx.x;
  if ((tid & 63) == 0) red[tid >> 6] = m;
  __syncthreads();
  if (tid == 0) {
    float bm = fmaxf(fmaxf(red[0], red[1]), fmaxf(red[2], red[3]));
    condAtomicMax(amax, bm);
  }
}

__device__ __forceinline__ float fq1(float v, float s, float inv) {
  return fminf(fmaxf(rintf(v * inv), -127.f), 127.f) * s;
}

__global__ __launch_bounds__(256) void k_quant_f32(const float* __restrict__ x, u16* __restrict__ q, int n4,
                                                   const u32* __restrict__ amax) {
  float s = fmaxf(__uint_as_float(*amax) / 127.0f, 1e-8f);
  float inv = 1.0f / s;
  int stride = gridDim.x * blockDim.x;
  for (int i = blockIdx.x * blockDim.x + threadIdx.x; i < n4; i += stride) {
    float4 v = ((const float4*)x)[i];
    ushort4 o;
    o.x = f2bf(fq1(v.x, s, inv));
    o.y = f2bf(fq1(v.y, s, inv));
    o.z = f2bf(fq1(v.z, s, inv));
    o.w = f2bf(fq1(v.w, s, inv));
    ((ushort4*)q)[i] = o;
  }
}

__global__ __launch_bounds__(256) void k_quant_bf16(u16* __restrict__ x, int n8, const u32* __restrict__ amax) {
  float s = fmaxf(__uint_as_float(*amax) / 127.0f, 1e-8f);
  float inv = 1.0f / s;
  int stride = gridDim.x * blockDim.x;
  for (int i = blockIdx.x * blockDim.x + threadIdx.x; i < n8; i += stride) {
    uint4 d = ((uint4*)x)[i];
    u16* e = (u16*)&d;
#pragma unroll
    for (int j = 0; j < 8; j++) e[j] = f2bf(fq1(bf2f(e[j]), s, inv));
    ((uint4*)x)[i] = d;
  }
}

// LayerNorm row (C=1024) + global absmax of output (block-reduced, low-contention)
__global__ __launch_bounds__(256) void k_ln(const float* __restrict__ x, const float* __restrict__ g,
                                            const float* __restrict__ b, float* __restrict__ y,
                                            u32* __restrict__ amax) {
  int row = blockIdx.x;
  int t = threadIdx.x;
  float4 v = ((const float4*)(x + (long)row * C_))[t];
  float s1 = v.x + v.y + v.z + v.w;
  float s2 = v.x * v.x + v.y * v.y + v.z * v.z + v.w * v.w;
  s1 = wredSum(s1);
  s2 = wredSum(s2);
  __shared__ float red[8];
  int wid = t >> 6, lane = t & 63;
  if (lane == 0) { red[wid] = s1; red[4 + wid] = s2; }
  __syncthreads();
  s1 = red[0] + red[1] + red[2] + red[3];
  s2 = red[4] + red[5] + red[6] + red[7];
  float mean = s1 * (1.0f / C_);
  float var = s2 * (1.0f / C_) - mean * mean;
  float inv = rsqrtf(var + 1e-5f);
  float4 gv = ((const float4*)g)[t];
  float4 bv = ((const float4*)b)[t];
  float4 o;
  o.x = (v.x - mean) * inv * gv.x + bv.x;
  o.y = (v.y - mean) * inv * gv.y + bv.y;
  o.z = (v.z - mean) * inv * gv.z + bv.z;
  o.w = (v.w - mean) * inv * gv.w + bv.w;
  ((float4*)(y + (long)row * C_))[t] = o;
  float m = fmaxf(fmaxf(fabsf(o.x), fabsf(o.y)), fmaxf(fabsf(o.z), fabsf(o.w)));
  m = wredMax(m);
  __syncthreads();  // all threads done reading red[] for the sums
  if (lane == 0) red[wid] = m;
  __syncthreads();
  if (t == 0) {
    float bm = fmaxf(fmaxf(red[0], red[1]), fmaxf(red[2], red[3]));
    condAtomicMax(amax, bm);
  }
}

// softmax over rows of 512, bf16 in-place; one wave per row
__global__ __launch_bounds__(256) void k_softmax(u16* __restrict__ S) {
  int r = blockIdx.x * 4 + (threadIdx.x >> 6);
  int lane = threadIdx.x & 63;
  u16* row = S + (long)r * T_ + lane * 8;
  uint4 d = *(const uint4*)row;
  u16* e = (u16*)&d;
  float v[8];
  float mx = -3.0e38f;
#pragma unroll
  for (int j = 0; j < 8; j++) { v[j] = bf2f(e[j]); mx = fmaxf(mx, v[j]); }
  mx = wredMax(mx);
  float sum = 0.f;
#pragma unroll
  for (int j = 0; j < 8; j++) { v[j] = expf(v[j] - mx); sum += v[j]; }
  sum = wredSum(sum);
  float inv = 1.0f / sum;
#pragma unroll
  for (int j = 0; j < 8; j++) e[j] = f2bf(v[j] * inv);
  *(uint4*)row = d;
}

// ---------------- unified MFMA GEMM ----------------
// C[M,N] = A[M,K] * B^T + epilogue.  B normally [N,K] row-major; EPI==5: B is [K,N].
// Staging via global_load_lds (16B/lane, linear LDS) except EPI5's B (transpose).
// 4 waves as 2x2; wave tile (BM/2) x (BN/2).
// EPI: 0 = +bias -> bf16
//      1 = +bias +resid(f32) -> f32
//      2 = +bias, gelu, absmax -> bf16
//      3 = +bias +resid(f32) -> f32 (final output)
//      4 = *scale + mask-ext -> bf16 (scores)
//      5 = absmax -> bf16 (PV; B in [K,N])
template <int BM, int BN, int EPI>
__global__ __launch_bounds__(256) void k_gemm(
    const u16* __restrict__ A, int lda, long sAb, long sAh,
    const u16* __restrict__ Bm, int ldb, long sBb, long sBh,
    const float* __restrict__ bias,
    void* __restrict__ Cp, int ldc, long sCb, long sCh,
    int M, int N, int K, int bH,
    const float* __restrict__ resid,
    u32* __restrict__ amax,
    const float* __restrict__ mask, float scale) {
  constexpr int BK = 32;
  constexpr int MF = (BM / 2) / 16;
  constexpr int NF = (BN / 2) / 16;
  __shared__ u16 As[BM][BK];
  __shared__ u16 Bs[BN][BK];
  const int tid = threadIdx.x;
  const int wid = tid >> 6, lane = tid & 63;
  const int wr = wid >> 1, wc = wid & 1;
  const int bz = blockIdx.z;
  const int bb = bz / bH, hh = bz % bH;
  const u16* Ab = A + bb * sAb + hh * sAh + (long)blockIdx.y * BM * lda;
  const u16* Bb;
  if (EPI == 5)
    Bb = Bm + bb * sBb + hh * sBh + blockIdx.x * BN;  // [K,N]: column offset
  else
    Bb = Bm + bb * sBb + hh * sBh + (long)blockIdx.x * BN * ldb;

  f32x4 acc[MF][NF];
#pragma unroll
  for (int m = 0; m < MF; m++)
#pragma unroll
    for (int n = 0; n < NF; n++) acc[m][n] = (f32x4){0.f, 0.f, 0.f, 0.f};

  const int lr = lane & 15;
  const int lk = (lane >> 4) * 8;
  const int lrow = lane >> 2;        // 0..15, row within a 16-row stage stripe
  const int lcol8 = (lane & 3) * 8;  // u16 col offset within BK

  for (int k0 = 0; k0 < K; k0 += BK) {
    __syncthreads();
    // stage A: global_load_lds, wave `wid` covers rows [wid*(BM/4), +BM/4)
#pragma unroll
    for (int i = 0; i < BM / 64; ++i) {
      int r = wid * (BM / 4) + i * 16;
      gload16(Ab + (long)(r + lrow) * lda + k0 + lcol8, &As[r][0]);
    }
    if (EPI == 5) {
      // Bs[n][kk] = Bb[(k0+kk)*ldb + n]; BN==64 here (transpose, reg-staged)
      int kk = tid >> 3;
      int n0 = (tid & 7) * 8;
      uint4 t4 = *(const uint4*)(Bb + (long)(k0 + kk) * ldb + n0);
      u16* tv = (u16*)&t4;
#pragma unroll
      for (int j = 0; j < 8; j++) Bs[n0 + j][kk] = tv[j];
    } else {
#pragma unroll
      for (int i = 0; i < BN / 64; ++i) {
        int r = wid * (BN / 4) + i * 16;
        gload16(Bb + (long)(r + lrow) * ldb + k0 + lcol8, &Bs[r][0]);
      }
    }
    __syncthreads();

    bf16x8 af[MF], bfr[NF];
#pragma unroll
    for (int m = 0; m < MF; m++) af[m] = *(const bf16x8*)&As[wr * (BM / 2) + m * 16 + lr][lk];
#pragma unroll
    for (int n = 0; n < NF; n++) bfr[n] = *(const bf16x8*)&Bs[wc * (BN / 2) + n * 16 + lr][lk];
#pragma unroll
    for (int m = 0; m < MF; m++)
#pragma unroll
      for (int n = 0; n < NF; n++)
        acc[m][n] = __builtin_amdgcn_mfma_f32_16x16x32_bf16(af[m], bfr[n], acc[m][n], 0, 0, 0);
  }

  const int rowBase = blockIdx.y * BM + wr * (BM / 2);
  const int colBase = blockIdx.x * BN + wc * (BN / 2);
  const long cb = bb * sCb + hh * sCh;
  float lmax = 0.f;
#pragma unroll
  for (int m = 0; m < MF; m++) {
    int row0 = rowBase + m * 16 + (lane >> 4) * 4;
#pragma unroll
    for (int n = 0; n < NF; n++) {
      int col = colBase + n * 16 + lr;
      float bs = 0.f, ext = 0.f;
      if (EPI == 0 || EPI == 1 || EPI == 2 || EPI == 3) bs = bias[col];
      if (EPI == 4) ext = (1.0f - mask[bb * T_ + col]) * -10000.0f;
#pragma unroll
      for (int j = 0; j < 4; j++) {
        int row = row0 + j;
        long idx = cb + (long)row * ldc + col;
        float v = acc[m][n][j];
        if (EPI == 0) {
          ((u16*)Cp)[idx] = f2bf(v + bs);
        } else if (EPI == 1) {
          ((float*)Cp)[idx] = v + bs + resid[idx];
        } else if (EPI == 2) {
          v += bs;
          v = 0.5f * v * (1.0f + erff(v * 0.70710678118f));
          lmax = fmaxf(lmax, fabsf(v));
          ((u16*)Cp)[idx] = f2bf(v);
        } else if (EPI == 3) {
          ((float*)Cp)[idx] = v + bs + resid[idx];
        } else if (EPI == 4) {
          ((u16*)Cp)[idx] = f2bf(v * scale + ext);
        } else {
          lmax = fmaxf(lmax, fabsf(v));
          ((u16*)Cp)[idx] = f2bf(v);
        }
      }
    }
  }
  if (EPI == 2 || EPI == 5) {
    __shared__ float redm[4];
    float wm = wredMax(lmax);
    if (lane == 0) redm[wid] = wm;
    __syncthreads();
    if (tid == 0) {
      float bm = fmaxf(fmaxf(redm[0], redm[1]), fmaxf(redm[2], redm[3]));
      condAtomicMax(amax, bm);
    }
  }
}

// ---------------- host ----------------
extern "C" void kernel_launch(void* const* d_in, const int* in_sizes, int n_in,
                              void* d_out, int out_size, void* d_ws, size_t ws_size,
                              hipStream_t stream) {
  const float* hidden = (const float*)d_in[0];
  const float* mask = (const float*)d_in[1];
  const float* ln1g = (const float*)d_in[2];
  const float* ln1b = (const float*)d_in[3];
  const float* ln2g = (const float*)d_in[4];
  const float* ln2b = (const float*)d_in[5];
  const float* w_qkv = (const float*)d_in[6];
  const float* b_qkv = (const float*)d_in[7];
  const float* w_out = (const float*)d_in[8];
  const float* b_out = (const float*)d_in[9];
  const float* w1 = (const float*)d_in[10];
  const float* b1 = (const float*)d_in[11];
  const float* w2 = (const float*)d_in[12];
  const float* b2 = (const float*)d_in[13];

  char* ws = (char*)d_ws;
  u32* sc = (u32*)ws;  // [0]wqkv [1]wout [2]w1 [3]w2 [4]x1 [5]O [6]x2 [7]y1
  u16* wq_qkv = (u16*)(ws + 256);
  u16* wq_out = (u16*)(ws + 6291712);
  u16* wq_w1 = (u16*)(ws + 8388864);
  u16* wq_w2 = (u16*)(ws + 16777472);
  float* x1 = (float*)(ws + 25166080);   // also x2
  u16* xq = (u16*)(ws + 41943296);       // also x2q
  u16* qkv = (u16*)(ws + 50331904);
  u16* S = (u16*)(ws + 75497728);        // scores/P; later y1 (raw+quant)
  u16* O = (u16*)(ws + 142606592);
  float* hbuf = (float*)(ws + 150995200);
  // total ws use: 167,772,416 bytes

  k_init<<<1, 64, 0, stream>>>(sc);

  // weight fake-quant
  k_absmax<<<512, 256, 0, stream>>>(w_qkv, 3 * C_ * C_ / 4, sc + 0);
  k_absmax<<<512, 256, 0, stream>>>(w_out, C_ * C_ / 4, sc + 1);
  k_absmax<<<512, 256, 0, stream>>>(w1, I_ * C_ / 4, sc + 2);
  k_absmax<<<512, 256, 0, stream>>>(w2, C_ * I_ / 4, sc + 3);
  k_quant_f32<<<512, 256, 0, stream>>>(w_qkv, wq_qkv, 3 * C_ * C_ / 4, sc + 0);
  k_quant_f32<<<512, 256, 0, stream>>>(w_out, wq_out, C_ * C_ / 4, sc + 1);
  k_quant_f32<<<512, 256, 0, stream>>>(w1, wq_w1, I_ * C_ / 4, sc + 2);
  k_quant_f32<<<512, 256, 0, stream>>>(w2, wq_w2, C_ * I_ / 4, sc + 3);

  // LN1 + fq(x)
  k_ln<<<BT, 256, 0, stream>>>(hidden, ln1g, ln1b, x1, sc + 4);
  k_quant_f32<<<512, 256, 0, stream>>>(x1, xq, BT * C_ / 4, sc + 4);

  // qkv = xq @ wq_qkv^T + b  -> bf16 [4096,3072]
  k_gemm<128, 128, 0><<<dim3(24, 32, 1), 256, 0, stream>>>(
      xq, C_, 0, 0, wq_qkv, C_, 0, 0, b_qkv, qkv, 3 * C_, 0, 0,
      BT, 3 * C_, C_, 1, nullptr, nullptr, nullptr, 0.f);

  // scores = Q K^T * scale + ext -> bf16 [128][512][512]
  k_gemm<128, 128, 4><<<dim3(4, 4, NH), 256, 0, stream>>>(
      qkv, 3 * C_, (long)T_ * 3 * C_, Dh_,
      qkv + C_, 3 * C_, (long)T_ * 3 * C_, Dh_,
      nullptr,
      S, T_, (long)H_ * T_ * T_, (long)T_ * T_,
      T_, T_, Dh_, H_, nullptr, nullptr, mask, 0.125f);

  k_softmax<<<NH * T_ / 4, 256, 0, stream>>>(S);

  // O = P @ V  (B in [K,N])  -> bf16 [4096,1024] in (b,t,h*64+d) layout, + absmax
  k_gemm<128, 64, 5><<<dim3(1, 4, NH), 256, 0, stream>>>(
      S, T_, (long)H_ * T_ * T_, (long)T_ * T_,
      qkv + 2 * C_, 3 * C_, (long)T_ * 3 * C_, Dh_,
      nullptr,
      O, C_, (long)T_ * C_, (long)Dh_,
      T_, Dh_, T_, H_, nullptr, sc + 5, nullptr, 0.f);

  k_quant_bf16<<<512, 256, 0, stream>>>(O, BT * C_ / 8, sc + 5);

  // h = hidden + Oq @ wq_out^T + b  -> f32   (BM=64 -> grid 512 = 2 blocks/CU)
  k_gemm<64, 128, 1><<<dim3(8, 64, 1), 256, 0, stream>>>(
      O, C_, 0, 0, wq_out, C_, 0, 0, b_out, hbuf, C_, 0, 0,
      BT, C_, C_, 1, hidden, nullptr, nullptr, 0.f);

  // LN2 + fq
  k_ln<<<BT, 256, 0, stream>>>(hbuf, ln2g, ln2b, x1, sc + 6);
  k_quant_f32<<<512, 256, 0, stream>>>(x1, xq, BT * C_ / 4, sc + 6);

  // y1 = gelu(xq @ wq_w1^T + b1) -> bf16 [4096,4096], + absmax
  k_gemm<128, 128, 2><<<dim3(32, 32, 1), 256, 0, stream>>>(
      xq, C_, 0, 0, wq_w1, C_, 0, 0, b1, S, I_, 0, 0,
      BT, I_, C_, 1, nullptr, sc + 7, nullptr, 0.f);

  k_quant_bf16<<<512, 256, 0, stream>>>(S, BT * I_ / 8, sc + 7);

  // out = h + y1q @ wq_w2^T + b2 -> f32 d_out  (BM=64 -> grid 512 = 2 blocks/CU)
  k_gemm<64, 128, 3><<<dim3(8, 64, 1), 256, 0, stream>>>(
      S, I_, 0, 0, wq_w2, I_, 0, 0, b2, d_out, C_, 0, 0,
      BT, C_, I_, 1, hbuf, nullptr, nullptr, 0.f);
}

// Round 7
// 418.971 us; speedup vs baseline: 2.1426x; 1.0314x over previous
//
#include <hip/hip_runtime.h>

typedef __attribute__((ext_vector_type(8))) short bf16x8;
typedef __attribute__((ext_vector_type(4))) float f32x4;
typedef unsigned short u16;
typedef unsigned int u32;

#define B_ 8
#define T_ 512
#define C_ 1024
#define I_ 4096
#define H_ 16
#define Dh_ 64
#define BT (B_*T_)
#define NH (B_*H_)

// ---------------- helpers ----------------
__device__ __forceinline__ float bf2f(u16 u) {
  return __uint_as_float(((u32)u) << 16);
}
__device__ __forceinline__ u16 f2bf(float f) {
  u32 u = __float_as_uint(f);
  u32 r = u + 0x7FFFu + ((u >> 16) & 1u);
  return (u16)(r >> 16);
}
__device__ __forceinline__ float wredMax(float v) {
#pragma unroll
  for (int o = 32; o; o >>= 1) v = fmaxf(v, __shfl_xor(v, o));
  return v;
}
__device__ __forceinline__ float wredSum(float v) {
#pragma unroll
  for (int o = 32; o; o >>= 1) v += __shfl_xor(v, o);
  return v;
}
// Conditional atomic: only RMW if our value beats the currently visible max.
// Stale reads are always <= true max (monotone), so skipping is safe.
__device__ __forceinline__ void condAtomicMax(u32* amax, float bm) {
  u32 b = __float_as_uint(bm);  // bm >= 0 so uint compare == float compare
  if (b > *(volatile u32*)amax) atomicMax(amax, b);
}
// global -> LDS direct copy, 16B per lane; lds dest is wave-uniform base,
// lane l lands at base + l*16 bytes.
__device__ __forceinline__ void gload16(const void* g, void* l) {
  __builtin_amdgcn_global_load_lds((const __attribute__((address_space(1))) void*)g,
                                   (__attribute__((address_space(3))) void*)l, 16, 0, 0);
}

// ---------------- small kernels ----------------
__global__ void k_init(u32* s) { if (threadIdx.x < 16) s[threadIdx.x] = 0u; }

__global__ __launch_bounds__(256) void k_absmax(const float* __restrict__ x, int n4, u32* __restrict__ amax) {
  int stride = gridDim.x * blockDim.x;
  float m = 0.f;
  for (int i = blockIdx.x * blockDim.x + threadIdx.x; i < n4; i += stride) {
    float4 v = ((const float4*)x)[i];
    m = fmaxf(m, fmaxf(fmaxf(fabsf(v.x), fabsf(v.y)), fmaxf(fabsf(v.z), fabsf(v.w))));
  }
  m = wredMax(m);
  __shared__ float red[4];
  int tid = threadIdx.x;
  if ((tid & 63) == 0) red[tid >> 6] = m;
  __syncthreads();
  if (tid == 0) {
    float bm = fmaxf(fmaxf(red[0], red[1]), fmaxf(red[2], red[3]));
    condAtomicMax(amax, bm);
  }
}

__device__ __forceinline__ float fq1(float v, float s, float inv) {
  return fminf(fmaxf(rintf(v * inv), -127.f), 127.f) * s;
}

__global__ __launch_bounds__(256) void k_quant_f32(const float* __restrict__ x, u16* __restrict__ q, int n4,
                                                   const u32* __restrict__ amax) {
  float s = fmaxf(__uint_as_float(*amax) / 127.0f, 1e-8f);
  float inv = 1.0f / s;
  int stride = gridDim.x * blockDim.x;
  for (int i = blockIdx.x * blockDim.x + threadIdx.x; i < n4; i += stride) {
    float4 v = ((const float4*)x)[i];
    ushort4 o;
    o.x = f2bf(fq1(v.x, s, inv));
    o.y = f2bf(fq1(v.y, s, inv));
    o.z = f2bf(fq1(v.z, s, inv));
    o.w = f2bf(fq1(v.w, s, inv));
    ((ushort4*)q)[i] = o;
  }
}

__global__ __launch_bounds__(256) void k_quant_bf16(u16* __restrict__ x, int n8, const u32* __restrict__ amax) {
  float s = fmaxf(__uint_as_float(*amax) / 127.0f, 1e-8f);
  float inv = 1.0f / s;
  int stride = gridDim.x * blockDim.x;
  for (int i = blockIdx.x * blockDim.x + threadIdx.x; i < n8; i += stride) {
    uint4 d = ((uint4*)x)[i];
    u16* e = (u16*)&d;
#pragma unroll
    for (int j = 0; j < 8; j++) e[j] = f2bf(fq1(bf2f(e[j]), s, inv));
    ((uint4*)x)[i] = d;
  }
}

// LayerNorm row (C=1024) + global absmax of output (block-reduced, low-contention)
__global__ __launch_bounds__(256) void k_ln(const float* __restrict__ x, const float* __restrict__ g,
                                            const float* __restrict__ b, float* __restrict__ y,
                                            u32* __restrict__ amax) {
  int row = blockIdx.x;
  int t = threadIdx.x;
  float4 v = ((const float4*)(x + (long)row * C_))[t];
  float s1 = v.x + v.y + v.z + v.w;
  float s2 = v.x * v.x + v.y * v.y + v.z * v.z + v.w * v.w;
  s1 = wredSum(s1);
  s2 = wredSum(s2);
  __shared__ float red[8];
  int wid = t >> 6, lane = t & 63;
  if (lane == 0) { red[wid] = s1; red[4 + wid] = s2; }
  __syncthreads();
  s1 = red[0] + red[1] + red[2] + red[3];
  s2 = red[4] + red[5] + red[6] + red[7];
  float mean = s1 * (1.0f / C_);
  float var = s2 * (1.0f / C_) - mean * mean;
  float inv = rsqrtf(var + 1e-5f);
  float4 gv = ((const float4*)g)[t];
  float4 bv = ((const float4*)b)[t];
  float4 o;
  o.x = (v.x - mean) * inv * gv.x + bv.x;
  o.y = (v.y - mean) * inv * gv.y + bv.y;
  o.z = (v.z - mean) * inv * gv.z + bv.z;
  o.w = (v.w - mean) * inv * gv.w + bv.w;
  ((float4*)(y + (long)row * C_))[t] = o;
  float m = fmaxf(fmaxf(fabsf(o.x), fabsf(o.y)), fmaxf(fabsf(o.z), fabsf(o.w)));
  m = wredMax(m);
  __syncthreads();  // all threads done reading red[] for the sums
  if (lane == 0) red[wid] = m;
  __syncthreads();
  if (t == 0) {
    float bm = fmaxf(fmaxf(red[0], red[1]), fmaxf(red[2], red[3]));
    condAtomicMax(amax, bm);
  }
}

// softmax over rows of 512, bf16 in-place; one wave per row
__global__ __launch_bounds__(256) void k_softmax(u16* __restrict__ S) {
  int r = blockIdx.x * 4 + (threadIdx.x >> 6);
  int lane = threadIdx.x & 63;
  u16* row = S + (long)r * T_ + lane * 8;
  uint4 d = *(const uint4*)row;
  u16* e = (u16*)&d;
  float v[8];
  float mx = -3.0e38f;
#pragma unroll
  for (int j = 0; j < 8; j++) { v[j] = bf2f(e[j]); mx = fmaxf(mx, v[j]); }
  mx = wredMax(mx);
  float sum = 0.f;
#pragma unroll
  for (int j = 0; j < 8; j++) { v[j] = expf(v[j] - mx); sum += v[j]; }
  sum = wredSum(sum);
  float inv = 1.0f / sum;
#pragma unroll
  for (int j = 0; j < 8; j++) e[j] = f2bf(v[j] * inv);
  *(uint4*)row = d;
}

// ---------------- unified MFMA GEMM ----------------
// C[M,N] = A[M,K] * B^T + epilogue.  B normally [N,K] row-major; EPI==5: B is [K,N].
// BK=64 (128B rows) with XOR slot-swizzle: element (r, slot) stored at
// phys slot = slot ^ (r&7).  Staging via global_load_lds with PRE-SWIZZLED
// per-lane global source (linear LDS dest); ds_read uses the same XOR ->
// rows 0..7 of a fragment read hit 8 distinct 16B slots = conflict-free.
// SWZ: bijective XCD chunk-swizzle of (bx,by) for L2 A-panel locality.
// EPI: 0 = +bias -> bf16
//      1 = +bias +resid(f32) -> f32
//      2 = +bias, gelu, absmax -> bf16
//      3 = +bias +resid(f32) -> f32 (final output)
//      4 = *scale + mask-ext -> bf16 (scores)
//      5 = absmax -> bf16 (PV; B in [K,N])
template <int BM, int BN, int EPI, bool SWZ>
__global__ __launch_bounds__(256) void k_gemm(
    const u16* __restrict__ A, int lda, long sAb, long sAh,
    const u16* __restrict__ Bm, int ldb, long sBb, long sBh,
    const float* __restrict__ bias,
    void* __restrict__ Cp, int ldc, long sCb, long sCh,
    int M, int N, int K, int bH,
    const float* __restrict__ resid,
    u32* __restrict__ amax,
    const float* __restrict__ mask, float scale) {
  constexpr int BK = 64;
  constexpr int MF = (BM / 2) / 16;
  constexpr int NF = (BN / 2) / 16;
  __shared__ u16 As[BM * BK];
  __shared__ u16 Bs[BN * BK];
  const int tid = threadIdx.x;
  const int wid = tid >> 6, lane = tid & 63;
  const int wr = wid >> 1, wc = wid & 1;
  const int bz = blockIdx.z;
  const int bb = bz / bH, hh = bz % bH;

  int bx = blockIdx.x, by = blockIdx.y;
  if (SWZ) {
    int gx = gridDim.x;
    int nwg = gx * gridDim.y;       // must be % 8 == 0 (all SWZ call sites are)
    int bid = by * gx + bx;
    int cpx = nwg >> 3;
    int swz = (bid & 7) * cpx + (bid >> 3);
    bx = swz % gx;
    by = swz / gx;
  }

  const u16* Ab = A + bb * sAb + hh * sAh + (long)by * BM * lda;
  const u16* Bb;
  if (EPI == 5)
    Bb = Bm + bb * sBb + hh * sBh + bx * BN;  // [K,N]: column offset
  else
    Bb = Bm + bb * sBb + hh * sBh + (long)bx * BN * ldb;

  f32x4 acc[MF][NF];
#pragma unroll
  for (int m = 0; m < MF; m++)
#pragma unroll
    for (int n = 0; n < NF; n++) acc[m][n] = (f32x4){0.f, 0.f, 0.f, 0.f};

  const int lr = lane & 15;
  // pre-swizzled staging source offsets (stripe base is 8-row aligned, so
  // row&7 == lane>>3 independent of stripe)
  const int l8 = lane >> 3;              // row within 8-row stripe
  const int s8 = (lane & 7) ^ l8;        // swizzled slot to fetch
  const long aoff = (long)l8 * lda + (s8 << 3);
  const long boff = (long)l8 * ldb + (s8 << 3);

  for (int k0 = 0; k0 < K; k0 += BK) {
    __syncthreads();
    // stage A: wave wid covers rows [wid*(BM/4), +BM/4), 8 rows per gload
#pragma unroll
    for (int i = 0; i < BM / 32; ++i) {
      int R0 = wid * (BM / 4) + i * 8;
      gload16(Ab + (long)R0 * lda + k0 + aoff, &As[R0 * 64]);
    }
    if (EPI == 5) {
      // Bs[n][kk] = Bb[(k0+kk)*ldb + n], swizzled scatter (BN==64)
      int kk = tid >> 2;
      int sp = kk >> 3, k7 = kk & 7;
#pragma unroll
      for (int h = 0; h < 2; ++h) {
        int n0 = ((tid & 3) + h * 4) * 8;
        uint4 t4 = *(const uint4*)(Bb + (long)(k0 + kk) * ldb + n0);
        u16* tv = (u16*)&t4;
#pragma unroll
        for (int j = 0; j < 8; j++)
          Bs[(n0 + j) * 64 + ((sp ^ j) << 3) + k7] = tv[j];
      }
    } else {
#pragma unroll
      for (int i = 0; i < BN / 32; ++i) {
        int R0 = wid * (BN / 4) + i * 8;
        gload16(Bb + (long)R0 * ldb + k0 + boff, &Bs[R0 * 64]);
      }
    }
    __syncthreads();

#pragma unroll
    for (int kk = 0; kk < 2; ++kk) {
      const int sl = (kk << 2) + (lane >> 4);
      const int sf = (sl ^ (lr & 7)) << 3;
      bf16x8 af[MF], bfr[NF];
#pragma unroll
      for (int m = 0; m < MF; m++)
        af[m] = *(const bf16x8*)&As[(wr * (BM / 2) + m * 16 + lr) * 64 + sf];
#pragma unroll
      for (int n = 0; n < NF; n++)
        bfr[n] = *(const bf16x8*)&Bs[(wc * (BN / 2) + n * 16 + lr) * 64 + sf];
#pragma unroll
      for (int m = 0; m < MF; m++)
#pragma unroll
        for (int n = 0; n < NF; n++)
          acc[m][n] = __builtin_amdgcn_mfma_f32_16x16x32_bf16(af[m], bfr[n], acc[m][n], 0, 0, 0);
    }
  }

  const int rowBase = by * BM + wr * (BM / 2);
  const int colBase = bx * BN + wc * (BN / 2);
  const long cb = bb * sCb + hh * sCh;
  float lmax = 0.f;
#pragma unroll
  for (int m = 0; m < MF; m++) {
    int row0 = rowBase + m * 16 + (lane >> 4) * 4;
#pragma unroll
    for (int n = 0; n < NF; n++) {
      int col = colBase + n * 16 + lr;
      float bs = 0.f, ext = 0.f;
      if (EPI == 0 || EPI == 1 || EPI == 2 || EPI == 3) bs = bias[col];
      if (EPI == 4) ext = (1.0f - mask[bb * T_ + col]) * -10000.0f;
#pragma unroll
      for (int j = 0; j < 4; j++) {
        int row = row0 + j;
        long idx = cb + (long)row * ldc + col;
        float v = acc[m][n][j];
        if (EPI == 0) {
          ((u16*)Cp)[idx] = f2bf(v + bs);
        } else if (EPI == 1) {
          ((float*)Cp)[idx] = v + bs + resid[idx];
        } else if (EPI == 2) {
          v += bs;
          v = 0.5f * v * (1.0f + erff(v * 0.70710678118f));
          lmax = fmaxf(lmax, fabsf(v));
          ((u16*)Cp)[idx] = f2bf(v);
        } else if (EPI == 3) {
          ((float*)Cp)[idx] = v + bs + resid[idx];
        } else if (EPI == 4) {
          ((u16*)Cp)[idx] = f2bf(v * scale + ext);
        } else {
          lmax = fmaxf(lmax, fabsf(v));
          ((u16*)Cp)[idx] = f2bf(v);
        }
      }
    }
  }
  if (EPI == 2 || EPI == 5) {
    __shared__ float redm[4];
    float wm = wredMax(lmax);
    if (lane == 0) redm[wid] = wm;
    __syncthreads();
    if (tid == 0) {
      float bm = fmaxf(fmaxf(redm[0], redm[1]), fmaxf(redm[2], redm[3]));
      condAtomicMax(amax, bm);
    }
  }
}

// ---------------- host ----------------
extern "C" void kernel_launch(void* const* d_in, const int* in_sizes, int n_in,
                              void* d_out, int out_size, void* d_ws, size_t ws_size,
                              hipStream_t stream) {
  const float* hidden = (const float*)d_in[0];
  const float* mask = (const float*)d_in[1];
  const float* ln1g = (const float*)d_in[2];
  const float* ln1b = (const float*)d_in[3];
  const float* ln2g = (const float*)d_in[4];
  const float* ln2b = (const float*)d_in[5];
  const float* w_qkv = (const float*)d_in[6];
  const float* b_qkv = (const float*)d_in[7];
  const float* w_out = (const float*)d_in[8];
  const float* b_out = (const float*)d_in[9];
  const float* w1 = (const float*)d_in[10];
  const float* b1 = (const float*)d_in[11];
  const float* w2 = (const float*)d_in[12];
  const float* b2 = (const float*)d_in[13];

  char* ws = (char*)d_ws;
  u32* sc = (u32*)ws;  // [0]wqkv [1]wout [2]w1 [3]w2 [4]x1 [5]O [6]x2 [7]y1
  u16* wq_qkv = (u16*)(ws + 256);
  u16* wq_out = (u16*)(ws + 6291712);
  u16* wq_w1 = (u16*)(ws + 8388864);
  u16* wq_w2 = (u16*)(ws + 16777472);
  float* x1 = (float*)(ws + 25166080);   // also x2
  u16* xq = (u16*)(ws + 41943296);       // also x2q
  u16* qkv = (u16*)(ws + 50331904);
  u16* S = (u16*)(ws + 75497728);        // scores/P; later y1 (raw+quant)
  u16* O = (u16*)(ws + 142606592);
  float* hbuf = (float*)(ws + 150995200);
  // total ws use: 167,772,416 bytes

  k_init<<<1, 64, 0, stream>>>(sc);

  // weight fake-quant
  k_absmax<<<512, 256, 0, stream>>>(w_qkv, 3 * C_ * C_ / 4, sc + 0);
  k_absmax<<<512, 256, 0, stream>>>(w_out, C_ * C_ / 4, sc + 1);
  k_absmax<<<512, 256, 0, stream>>>(w1, I_ * C_ / 4, sc + 2);
  k_absmax<<<512, 256, 0, stream>>>(w2, C_ * I_ / 4, sc + 3);
  k_quant_f32<<<512, 256, 0, stream>>>(w_qkv, wq_qkv, 3 * C_ * C_ / 4, sc + 0);
  k_quant_f32<<<512, 256, 0, stream>>>(w_out, wq_out, C_ * C_ / 4, sc + 1);
  k_quant_f32<<<512, 256, 0, stream>>>(w1, wq_w1, I_ * C_ / 4, sc + 2);
  k_quant_f32<<<512, 256, 0, stream>>>(w2, wq_w2, C_ * I_ / 4, sc + 3);

  // LN1 + fq(x)
  k_ln<<<BT, 256, 0, stream>>>(hidden, ln1g, ln1b, x1, sc + 4);
  k_quant_f32<<<512, 256, 0, stream>>>(x1, xq, BT * C_ / 4, sc + 4);

  // qkv = xq @ wq_qkv^T + b  -> bf16 [4096,3072]
  k_gemm<128, 128, 0, true><<<dim3(24, 32, 1), 256, 0, stream>>>(
      xq, C_, 0, 0, wq_qkv, C_, 0, 0, b_qkv, qkv, 3 * C_, 0, 0,
      BT, 3 * C_, C_, 1, nullptr, nullptr, nullptr, 0.f);

  // scores = Q K^T * scale + ext -> bf16 [128][512][512]
  k_gemm<128, 128, 4, false><<<dim3(4, 4, NH), 256, 0, stream>>>(
      qkv, 3 * C_, (long)T_ * 3 * C_, Dh_,
      qkv + C_, 3 * C_, (long)T_ * 3 * C_, Dh_,
      nullptr,
      S, T_, (long)H_ * T_ * T_, (long)T_ * T_,
      T_, T_, Dh_, H_, nullptr, nullptr, mask, 0.125f);

  k_softmax<<<NH * T_ / 4, 256, 0, stream>>>(S);

  // O = P @ V  (B in [K,N])  -> bf16 [4096,1024] in (b,t,h*64+d) layout, + absmax
  k_gemm<128, 64, 5, false><<<dim3(1, 4, NH), 256, 0, stream>>>(
      S, T_, (long)H_ * T_ * T_, (long)T_ * T_,
      qkv + 2 * C_, 3 * C_, (long)T_ * 3 * C_, Dh_,
      nullptr,
      O, C_, (long)T_ * C_, (long)Dh_,
      T_, Dh_, T_, H_, nullptr, sc + 5, nullptr, 0.f);

  k_quant_bf16<<<512, 256, 0, stream>>>(O, BT * C_ / 8, sc + 5);

  // h = hidden + Oq @ wq_out^T + b  -> f32
  k_gemm<64, 128, 1, true><<<dim3(8, 64, 1), 256, 0, stream>>>(
      O, C_, 0, 0, wq_out, C_, 0, 0, b_out, hbuf, C_, 0, 0,
      BT, C_, C_, 1, hidden, nullptr, nullptr, 0.f);

  // LN2 + fq
  k_ln<<<BT, 256, 0, stream>>>(hbuf, ln2g, ln2b, x1, sc + 6);
  k_quant_f32<<<512, 256, 0, stream>>>(x1, xq, BT * C_ / 4, sc + 6);

  // y1 = gelu(xq @ wq_w1^T + b1) -> bf16 [4096,4096], + absmax
  k_gemm<128, 128, 2, true><<<dim3(32, 32, 1), 256, 0, stream>>>(
      xq, C_, 0, 0, wq_w1, C_, 0, 0, b1, S, I_, 0, 0,
      BT, I_, C_, 1, nullptr, sc + 7, nullptr, 0.f);

  k_quant_bf16<<<512, 256, 0, stream>>>(S, BT * I_ / 8, sc + 7);

  // out = h + y1q @ wq_w2^T + b2 -> f32 d_out
  k_gemm<64, 128, 3, true><<<dim3(8, 64, 1), 256, 0, stream>>>(
      S, I_, 0, 0, wq_w2, I_, 0, 0, b2, d_out, C_, 0, 0,
      BT, C_, I_, 1, hbuf, nullptr, nullptr, 0.f);
}

// Round 8
// 369.572 us; speedup vs baseline: 2.4290x; 1.1337x over previous
//
#include <hip/hip_runtime.h>

typedef __attribute__((ext_vector_type(8))) short bf16x8;
typedef __attribute__((ext_vector_type(4))) float f32x4;
typedef unsigned short u16;
typedef unsigned int u32;

#define B_ 8
#define T_ 512
#define C_ 1024
#define I_ 4096
#define H_ 16
#define Dh_ 64
#define BT (B_*T_)
#define NH (B_*H_)

// ---------------- helpers ----------------
__device__ __forceinline__ float bf2f(u16 u) {
  return __uint_as_float(((u32)u) << 16);
}
__device__ __forceinline__ u16 f2bf(float f) {
  u32 u = __float_as_uint(f);
  u32 r = u + 0x7FFFu + ((u >> 16) & 1u);
  return (u16)(r >> 16);
}
__device__ __forceinline__ float wredMax(float v) {
#pragma unroll
  for (int o = 32; o; o >>= 1) v = fmaxf(v, __shfl_xor(v, o));
  return v;
}
__device__ __forceinline__ float wredSum(float v) {
#pragma unroll
  for (int o = 32; o; o >>= 1) v += __shfl_xor(v, o);
  return v;
}
// Conditional atomic: only RMW if our value beats the currently visible max.
// Stale reads are always <= true max (monotone), so skipping is safe.
__device__ __forceinline__ void condAtomicMax(u32* amax, float bm) {
  u32 b = __float_as_uint(bm);  // bm >= 0 so uint compare == float compare
  if (b > *(volatile u32*)amax) atomicMax(amax, b);
}
// global -> LDS direct copy, 16B per lane; lds dest is wave-uniform base,
// lane l lands at base + l*16 bytes.
__device__ __forceinline__ void gload16(const void* g, void* l) {
  __builtin_amdgcn_global_load_lds((const __attribute__((address_space(1))) void*)g,
                                   (__attribute__((address_space(3))) void*)l, 16, 0, 0);
}

// ---------------- small kernels ----------------
__global__ void k_init(u32* s) { if (threadIdx.x < 16) s[threadIdx.x] = 0u; }

// absmax of 4 independent f32 arrays -> amax[0..3]
__global__ __launch_bounds__(256) void k_absmax4(
    const float* __restrict__ p0, int n0,
    const float* __restrict__ p1, int n1,
    const float* __restrict__ p2, int n2,
    const float* __restrict__ p3, int n3,
    u32* __restrict__ amax) {
  int stride = gridDim.x * blockDim.x;
  int gid = blockIdx.x * blockDim.x + threadIdx.x;
  float m0 = 0.f, m1 = 0.f, m2 = 0.f, m3 = 0.f;
  for (int i = gid; i < n0; i += stride) {
    float4 v = ((const float4*)p0)[i];
    m0 = fmaxf(m0, fmaxf(fmaxf(fabsf(v.x), fabsf(v.y)), fmaxf(fabsf(v.z), fabsf(v.w))));
  }
  for (int i = gid; i < n1; i += stride) {
    float4 v = ((const float4*)p1)[i];
    m1 = fmaxf(m1, fmaxf(fmaxf(fabsf(v.x), fabsf(v.y)), fmaxf(fabsf(v.z), fabsf(v.w))));
  }
  for (int i = gid; i < n2; i += stride) {
    float4 v = ((const float4*)p2)[i];
    m2 = fmaxf(m2, fmaxf(fmaxf(fabsf(v.x), fabsf(v.y)), fmaxf(fabsf(v.z), fabsf(v.w))));
  }
  for (int i = gid; i < n3; i += stride) {
    float4 v = ((const float4*)p3)[i];
    m3 = fmaxf(m3, fmaxf(fmaxf(fabsf(v.x), fabsf(v.y)), fmaxf(fabsf(v.z), fabsf(v.w))));
  }
  m0 = wredMax(m0); m1 = wredMax(m1); m2 = wredMax(m2); m3 = wredMax(m3);
  __shared__ float red[4][4];
  int wid = threadIdx.x >> 6, lane = threadIdx.x & 63;
  if (lane == 0) { red[wid][0] = m0; red[wid][1] = m1; red[wid][2] = m2; red[wid][3] = m3; }
  __syncthreads();
  if (threadIdx.x < 4) {
    int j = threadIdx.x;
    float bm = fmaxf(fmaxf(red[0][j], red[1][j]), fmaxf(red[2][j], red[3][j]));
    condAtomicMax(amax + j, bm);
  }
}

__device__ __forceinline__ float fq1(float v, float s, float inv) {
  return fminf(fmaxf(rintf(v * inv), -127.f), 127.f) * s;
}

// fake-quant 4 independent f32 arrays -> bf16, scales from amax[0..3]
__global__ __launch_bounds__(256) void k_quant4(
    const float* __restrict__ p0, u16* __restrict__ q0, int n0,
    const float* __restrict__ p1, u16* __restrict__ q1, int n1,
    const float* __restrict__ p2, u16* __restrict__ q2, int n2,
    const float* __restrict__ p3, u16* __restrict__ q3, int n3,
    const u32* __restrict__ amax) {
  int stride = gridDim.x * blockDim.x;
  int gid = blockIdx.x * blockDim.x + threadIdx.x;
#define QLOOP(p, q, n, slot)                                                       \
  {                                                                                \
    float s = fmaxf(__uint_as_float(amax[slot]) / 127.0f, 1e-8f);                  \
    float inv = 1.0f / s;                                                          \
    for (int i = gid; i < n; i += stride) {                                        \
      float4 v = ((const float4*)p)[i];                                            \
      ushort4 o;                                                                   \
      o.x = f2bf(fq1(v.x, s, inv));                                                \
      o.y = f2bf(fq1(v.y, s, inv));                                                \
      o.z = f2bf(fq1(v.z, s, inv));                                                \
      o.w = f2bf(fq1(v.w, s, inv));                                                \
      ((ushort4*)q)[i] = o;                                                        \
    }                                                                              \
  }
  QLOOP(p0, q0, n0, 0)
  QLOOP(p1, q1, n1, 1)
  QLOOP(p2, q2, n2, 2)
  QLOOP(p3, q3, n3, 3)
#undef QLOOP
}

// fake-quant bf16 src -> bf16 dst (different buffers)
__global__ __launch_bounds__(256) void k_quant_b(const u16* __restrict__ x, u16* __restrict__ q, int n8,
                                                 const u32* __restrict__ amax) {
  float s = fmaxf(__uint_as_float(*amax) / 127.0f, 1e-8f);
  float inv = 1.0f / s;
  int stride = gridDim.x * blockDim.x;
  for (int i = blockIdx.x * blockDim.x + threadIdx.x; i < n8; i += stride) {
    uint4 d = ((const uint4*)x)[i];
    u16* e = (u16*)&d;
#pragma unroll
    for (int j = 0; j < 8; j++) e[j] = f2bf(fq1(bf2f(e[j]), s, inv));
    ((uint4*)q)[i] = d;
  }
}

// fake-quant bf16 in-place
__global__ __launch_bounds__(256) void k_quant_bf16(u16* __restrict__ x, int n8, const u32* __restrict__ amax) {
  float s = fmaxf(__uint_as_float(*amax) / 127.0f, 1e-8f);
  float inv = 1.0f / s;
  int stride = gridDim.x * blockDim.x;
  for (int i = blockIdx.x * blockDim.x + threadIdx.x; i < n8; i += stride) {
    uint4 d = ((uint4*)x)[i];
    u16* e = (u16*)&d;
#pragma unroll
    for (int j = 0; j < 8; j++) e[j] = f2bf(fq1(bf2f(e[j]), s, inv));
    ((uint4*)x)[i] = d;
  }
}

// LayerNorm row (C=1024) -> bf16 out + global absmax (block-reduced)
__global__ __launch_bounds__(256) void k_ln(const float* __restrict__ x, const float* __restrict__ g,
                                            const float* __restrict__ b, u16* __restrict__ y,
                                            u32* __restrict__ amax) {
  int row = blockIdx.x;
  int t = threadIdx.x;
  float4 v = ((const float4*)(x + (long)row * C_))[t];
  float s1 = v.x + v.y + v.z + v.w;
  float s2 = v.x * v.x + v.y * v.y + v.z * v.z + v.w * v.w;
  s1 = wredSum(s1);
  s2 = wredSum(s2);
  __shared__ float red[8];
  int wid = t >> 6, lane = t & 63;
  if (lane == 0) { red[wid] = s1; red[4 + wid] = s2; }
  __syncthreads();
  s1 = red[0] + red[1] + red[2] + red[3];
  s2 = red[4] + red[5] + red[6] + red[7];
  float mean = s1 * (1.0f / C_);
  float var = s2 * (1.0f / C_) - mean * mean;
  float inv = rsqrtf(var + 1e-5f);
  float4 gv = ((const float4*)g)[t];
  float4 bv = ((const float4*)b)[t];
  float4 o;
  o.x = (v.x - mean) * inv * gv.x + bv.x;
  o.y = (v.y - mean) * inv * gv.y + bv.y;
  o.z = (v.z - mean) * inv * gv.z + bv.z;
  o.w = (v.w - mean) * inv * gv.w + bv.w;
  ushort4 ob;
  ob.x = f2bf(o.x); ob.y = f2bf(o.y); ob.z = f2bf(o.z); ob.w = f2bf(o.w);
  ((ushort4*)(y + (long)row * C_))[t] = ob;
  float m = fmaxf(fmaxf(fabsf(o.x), fabsf(o.y)), fmaxf(fabsf(o.z), fabsf(o.w)));
  m = wredMax(m);
  __syncthreads();  // all threads done reading red[] for the sums
  if (lane == 0) red[wid] = m;
  __syncthreads();
  if (t == 0) {
    float bm = fmaxf(fmaxf(red[0], red[1]), fmaxf(red[2], red[3]));
    condAtomicMax(amax, bm);
  }
}

// softmax over rows of 512, bf16 in-place; one wave per row
__global__ __launch_bounds__(256) void k_softmax(u16* __restrict__ S) {
  int r = blockIdx.x * 4 + (threadIdx.x >> 6);
  int lane = threadIdx.x & 63;
  u16* row = S + (long)r * T_ + lane * 8;
  uint4 d = *(const uint4*)row;
  u16* e = (u16*)&d;
  float v[8];
  float mx = -3.0e38f;
#pragma unroll
  for (int j = 0; j < 8; j++) { v[j] = bf2f(e[j]); mx = fmaxf(mx, v[j]); }
  mx = wredMax(mx);
  float sum = 0.f;
#pragma unroll
  for (int j = 0; j < 8; j++) { v[j] = expf(v[j] - mx); sum += v[j]; }
  sum = wredSum(sum);
  float inv = 1.0f / sum;
#pragma unroll
  for (int j = 0; j < 8; j++) e[j] = f2bf(v[j] * inv);
  *(uint4*)row = d;
}

// ---------------- unified MFMA GEMM ----------------
// C[M,N] = A[M,K] * B^T + epilogue.  B normally [N,K] row-major; EPI==5: B is [K,N].
// BK=64 (128B rows) with XOR slot-swizzle: element (r, slot) stored at
// phys slot = slot ^ (r&7).  Staging via global_load_lds with PRE-SWIZZLED
// per-lane global source (linear LDS dest); ds_read uses the same XOR ->
// rows 0..7 of a fragment read hit 8 distinct 16B slots = conflict-free.
// SWZ: bijective XCD chunk-swizzle of (bx,by) for L2 A-panel locality.
// EPI: 0 = +bias -> bf16
//      1 = +bias +resid(f32) -> f32
//      2 = +bias, gelu(tanh-form), absmax -> bf16
//      3 = +bias +resid(f32) -> f32 (final output)
//      4 = *scale + mask-ext -> bf16 (scores)
//      5 = absmax -> bf16 (PV; B in [K,N])
template <int BM, int BN, int EPI, bool SWZ>
__global__ __launch_bounds__(256) void k_gemm(
    const u16* __restrict__ A, int lda, long sAb, long sAh,
    const u16* __restrict__ Bm, int ldb, long sBb, long sBh,
    const float* __restrict__ bias,
    void* __restrict__ Cp, int ldc, long sCb, long sCh,
    int M, int N, int K, int bH,
    const float* __restrict__ resid,
    u32* __restrict__ amax,
    const float* __restrict__ mask, float scale) {
  constexpr int BK = 64;
  constexpr int MF = (BM / 2) / 16;
  constexpr int NF = (BN / 2) / 16;
  __shared__ u16 As[BM * BK];
  __shared__ u16 Bs[BN * BK];
  const int tid = threadIdx.x;
  const int wid = tid >> 6, lane = tid & 63;
  const int wr = wid >> 1, wc = wid & 1;
  const int bz = blockIdx.z;
  const int bb = bz / bH, hh = bz % bH;

  int bx = blockIdx.x, by = blockIdx.y;
  if (SWZ) {
    int gx = gridDim.x;
    int nwg = gx * gridDim.y;       // must be % 8 == 0 (all SWZ call sites are)
    int bid = by * gx + bx;
    int cpx = nwg >> 3;
    int swz = (bid & 7) * cpx + (bid >> 3);
    bx = swz % gx;
    by = swz / gx;
  }

  const u16* Ab = A + bb * sAb + hh * sAh + (long)by * BM * lda;
  const u16* Bb;
  if (EPI == 5)
    Bb = Bm + bb * sBb + hh * sBh + bx * BN;  // [K,N]: column offset
  else
    Bb = Bm + bb * sBb + hh * sBh + (long)bx * BN * ldb;

  f32x4 acc[MF][NF];
#pragma unroll
  for (int m = 0; m < MF; m++)
#pragma unroll
    for (int n = 0; n < NF; n++) acc[m][n] = (f32x4){0.f, 0.f, 0.f, 0.f};

  const int lr = lane & 15;
  // pre-swizzled staging source offsets (stripe base is 8-row aligned, so
  // row&7 == lane>>3 independent of stripe)
  const int l8 = lane >> 3;              // row within 8-row stripe
  const int s8 = (lane & 7) ^ l8;        // swizzled slot to fetch
  const long aoff = (long)l8 * lda + (s8 << 3);
  const long boff = (long)l8 * ldb + (s8 << 3);

  for (int k0 = 0; k0 < K; k0 += BK) {
    __syncthreads();
    // stage A: wave wid covers rows [wid*(BM/4), +BM/4), 8 rows per gload
#pragma unroll
    for (int i = 0; i < BM / 32; ++i) {
      int R0 = wid * (BM / 4) + i * 8;
      gload16(Ab + (long)R0 * lda + k0 + aoff, &As[R0 * 64]);
    }
    if (EPI == 5) {
      // Bs[n][kk] = Bb[(k0+kk)*ldb + n], swizzled scatter (BN==64)
      int kk = tid >> 2;
      int sp = kk >> 3, k7 = kk & 7;
#pragma unroll
      for (int h = 0; h < 2; ++h) {
        int n0 = ((tid & 3) + h * 4) * 8;
        uint4 t4 = *(const uint4*)(Bb + (long)(k0 + kk) * ldb + n0);
        u16* tv = (u16*)&t4;
#pragma unroll
        for (int j = 0; j < 8; j++)
          Bs[(n0 + j) * 64 + ((sp ^ j) << 3) + k7] = tv[j];
      }
    } else {
#pragma unroll
      for (int i = 0; i < BN / 32; ++i) {
        int R0 = wid * (BN / 4) + i * 8;
        gload16(Bb + (long)R0 * ldb + k0 + boff, &Bs[R0 * 64]);
      }
    }
    __syncthreads();

#pragma unroll
    for (int kk = 0; kk < 2; ++kk) {
      const int sl = (kk << 2) + (lane >> 4);
      const int sf = (sl ^ (lr & 7)) << 3;
      bf16x8 af[MF], bfr[NF];
#pragma unroll
      for (int m = 0; m < MF; m++)
        af[m] = *(const bf16x8*)&As[(wr * (BM / 2) + m * 16 + lr) * 64 + sf];
#pragma unroll
      for (int n = 0; n < NF; n++)
        bfr[n] = *(const bf16x8*)&Bs[(wc * (BN / 2) + n * 16 + lr) * 64 + sf];
#pragma unroll
      for (int m = 0; m < MF; m++)
#pragma unroll
        for (int n = 0; n < NF; n++)
          acc[m][n] = __builtin_amdgcn_mfma_f32_16x16x32_bf16(af[m], bfr[n], acc[m][n], 0, 0, 0);
    }
  }

  const int rowBase = by * BM + wr * (BM / 2);
  const int colBase = bx * BN + wc * (BN / 2);
  const long cb = bb * sCb + hh * sCh;
  float lmax = 0.f;
#pragma unroll
  for (int m = 0; m < MF; m++) {
    int row0 = rowBase + m * 16 + (lane >> 4) * 4;
#pragma unroll
    for (int n = 0; n < NF; n++) {
      int col = colBase + n * 16 + lr;
      float bs = 0.f, ext = 0.f;
      if (EPI == 0 || EPI == 1 || EPI == 2 || EPI == 3) bs = bias[col];
      if (EPI == 4) ext = (1.0f - mask[bb * T_ + col]) * -10000.0f;
#pragma unroll
      for (int j = 0; j < 4; j++) {
        int row = row0 + j;
        long idx = cb + (long)row * ldc + col;
        float v = acc[m][n][j];
        if (EPI == 0) {
          ((u16*)Cp)[idx] = f2bf(v + bs);
        } else if (EPI == 1) {
          ((float*)Cp)[idx] = v + bs + resid[idx];
        } else if (EPI == 2) {
          v += bs;
          // gelu tanh-form: x * sigmoid(2*(0.79788456*(x+0.044715 x^3)))
          float x2 = v * v;
          float e = __expf(v * fmaf(-0.0713548755f, x2, -1.5957691216f));
          v = v * __builtin_amdgcn_rcpf(1.0f + e);
          lmax = fmaxf(fmaxf(lmax, v), 0.0f - v);  // v_max3
          ((u16*)Cp)[idx] = f2bf(v);
        } else if (EPI == 3) {
          ((float*)Cp)[idx] = v + bs + resid[idx];
        } else if (EPI == 4) {
          ((u16*)Cp)[idx] = f2bf(v * scale + ext);
        } else {
          lmax = fmaxf(fmaxf(lmax, v), 0.0f - v);  // v_max3
          ((u16*)Cp)[idx] = f2bf(v);
        }
      }
    }
  }
  if (EPI == 2 || EPI == 5) {
    __shared__ float redm[4];
    float wm = wredMax(lmax);
    if (lane == 0) redm[wid] = wm;
    __syncthreads();
    if (tid == 0) {
      float bm = fmaxf(fmaxf(redm[0], redm[1]), fmaxf(redm[2], redm[3]));
      condAtomicMax(amax, bm);
    }
  }
}

// ---------------- host ----------------
extern "C" void kernel_launch(void* const* d_in, const int* in_sizes, int n_in,
                              void* d_out, int out_size, void* d_ws, size_t ws_size,
                              hipStream_t stream) {
  const float* hidden = (const float*)d_in[0];
  const float* mask = (const float*)d_in[1];
  const float* ln1g = (const float*)d_in[2];
  const float* ln1b = (const float*)d_in[3];
  const float* ln2g = (const float*)d_in[4];
  const float* ln2b = (const float*)d_in[5];
  const float* w_qkv = (const float*)d_in[6];
  const float* b_qkv = (const float*)d_in[7];
  const float* w_out = (const float*)d_in[8];
  const float* b_out = (const float*)d_in[9];
  const float* w1 = (const float*)d_in[10];
  const float* b1 = (const float*)d_in[11];
  const float* w2 = (const float*)d_in[12];
  const float* b2 = (const float*)d_in[13];

  char* ws = (char*)d_ws;
  u32* sc = (u32*)ws;  // [0]wqkv [1]wout [2]w1 [3]w2 [4]x1 [5]O [6]x2 [7]y1
  u16* wq_qkv = (u16*)(ws + 256);
  u16* wq_out = (u16*)(ws + 6291712);
  u16* wq_w1 = (u16*)(ws + 8388864);
  u16* wq_w2 = (u16*)(ws + 16777472);
  u16* x1 = (u16*)(ws + 25166080);       // LN output, bf16 (also x2)
  u16* xq = (u16*)(ws + 41943296);       // also x2q
  u16* qkv = (u16*)(ws + 50331904);
  u16* S = (u16*)(ws + 75497728);        // scores/P; later y1 (raw+quant)
  u16* O = (u16*)(ws + 142606592);
  float* hbuf = (float*)(ws + 150995200);
  // total ws use: 167,772,416 bytes

  k_init<<<1, 64, 0, stream>>>(sc);

  // weight fake-quant (merged: 2 launches)
  k_absmax4<<<512, 256, 0, stream>>>(
      w_qkv, 3 * C_ * C_ / 4, w_out, C_ * C_ / 4, w1, I_ * C_ / 4, w2, C_ * I_ / 4, sc);
  k_quant4<<<512, 256, 0, stream>>>(
      w_qkv, wq_qkv, 3 * C_ * C_ / 4, w_out, wq_out, C_ * C_ / 4,
      w1, wq_w1, I_ * C_ / 4, w2, wq_w2, C_ * I_ / 4, sc);

  // LN1 (bf16 out) + fq(x)
  k_ln<<<BT, 256, 0, stream>>>(hidden, ln1g, ln1b, x1, sc + 4);
  k_quant_b<<<512, 256, 0, stream>>>(x1, xq, BT * C_ / 8, sc + 4);

  // qkv = xq @ wq_qkv^T + b  -> bf16 [4096,3072]
  k_gemm<128, 128, 0, true><<<dim3(24, 32, 1), 256, 0, stream>>>(
      xq, C_, 0, 0, wq_qkv, C_, 0, 0, b_qkv, qkv, 3 * C_, 0, 0,
      BT, 3 * C_, C_, 1, nullptr, nullptr, nullptr, 0.f);

  // scores = Q K^T * scale + ext -> bf16 [128][512][512]
  k_gemm<128, 128, 4, false><<<dim3(4, 4, NH), 256, 0, stream>>>(
      qkv, 3 * C_, (long)T_ * 3 * C_, Dh_,
      qkv + C_, 3 * C_, (long)T_ * 3 * C_, Dh_,
      nullptr,
      S, T_, (long)H_ * T_ * T_, (long)T_ * T_,
      T_, T_, Dh_, H_, nullptr, nullptr, mask, 0.125f);

  k_softmax<<<NH * T_ / 4, 256, 0, stream>>>(S);

  // O = P @ V  (B in [K,N])  -> bf16 [4096,1024] in (b,t,h*64+d) layout, + absmax
  k_gemm<128, 64, 5, false><<<dim3(1, 4, NH), 256, 0, stream>>>(
      S, T_, (long)H_ * T_ * T_, (long)T_ * T_,
      qkv + 2 * C_, 3 * C_, (long)T_ * 3 * C_, Dh_,
      nullptr,
      O, C_, (long)T_ * C_, (long)Dh_,
      T_, Dh_, T_, H_, nullptr, sc + 5, nullptr, 0.f);

  k_quant_bf16<<<512, 256, 0, stream>>>(O, BT * C_ / 8, sc + 5);

  // h = hidden + Oq @ wq_out^T + b  -> f32
  k_gemm<64, 128, 1, true><<<dim3(8, 64, 1), 256, 0, stream>>>(
      O, C_, 0, 0, wq_out, C_, 0, 0, b_out, hbuf, C_, 0, 0,
      BT, C_, C_, 1, hidden, nullptr, nullptr, 0.f);

  // LN2 (bf16 out) + fq
  k_ln<<<BT, 256, 0, stream>>>(hbuf, ln2g, ln2b, x1, sc + 6);
  k_quant_b<<<512, 256, 0, stream>>>(x1, xq, BT * C_ / 8, sc + 6);

  // y1 = gelu(xq @ wq_w1^T + b1) -> bf16 [4096,4096], + absmax
  k_gemm<128, 128, 2, true><<<dim3(32, 32, 1), 256, 0, stream>>>(
      xq, C_, 0, 0, wq_w1, C_, 0, 0, b1, S, I_, 0, 0,
      BT, I_, C_, 1, nullptr, sc + 7, nullptr, 0.f);

  k_quant_bf16<<<512, 256, 0, stream>>>(S, BT * I_ / 8, sc + 7);

  // out = h + y1q @ wq_w2^T + b2 -> f32 d_out
  k_gemm<64, 128, 3, true><<<dim3(8, 64, 1), 256, 0, stream>>>(
      S, I_, 0, 0, wq_w2, I_, 0, 0, b2, d_out, C_, 0, 0,
      BT, C_, I_, 1, hbuf, nullptr, nullptr, 0.f);
}